// Round 1
// baseline (2257.366 us; speedup 1.0000x reference)
//
#include <hip/hip_runtime.h>
#include <cstdint>
#include <cstddef>

// ---- problem constants ----
#define Bsz  2
#define Lseq 2048
#define DM   1024
#define DI   2048
#define NS   16
#define RR   64
#define BL   (Bsz * Lseq)   // 4096 rows

typedef unsigned short u16;
typedef __attribute__((ext_vector_type(8))) short short8;   // 8 bf16 (4 VGPRs)
typedef __attribute__((ext_vector_type(4))) float f32x4;    // 4 f32 acc

__device__ __forceinline__ u16 f32_to_bf16(float f) {
  union { float f; unsigned int u; } v; v.f = f;
  unsigned int lsb = (v.u >> 16) & 1u;
  v.u += 0x7fffu + lsb;           // round-to-nearest-even
  return (u16)(v.u >> 16);
}

// ---------------- f32 -> bf16 conversion ----------------
__global__ void cvt_f32_bf16(const float* __restrict__ src, u16* __restrict__ dst, int n) {
  int i = (blockIdx.x * blockDim.x + threadIdx.x) * 4;
  if (i + 4 <= n) {
    float4 v = *(const float4*)(src + i);
    dst[i + 0] = f32_to_bf16(v.x);
    dst[i + 1] = f32_to_bf16(v.y);
    dst[i + 2] = f32_to_bf16(v.z);
    dst[i + 3] = f32_to_bf16(v.w);
  } else {
    for (; i < n; ++i) dst[i] = f32_to_bf16(src[i]);
  }
}

// ---------------- 128x128-tile bf16 MFMA GEMM (m97 structure) ----------------
// C[m][n] = sum_k A[m][k] * Bt[n][k];  A: M x K bf16 row-major, Bt: N x K bf16 row-major.
// Output f32, column-split epilogue: n < split -> outA[m*ldA + n], else outB[m*ldB + n-split].
__device__ __forceinline__ void gload_lds16(const u16* g, u16* l) {
  __builtin_amdgcn_global_load_lds(
      (const __attribute__((address_space(1))) unsigned int*)g,
      (__attribute__((address_space(3))) unsigned int*)l,
      16, 0, 0);
}

__global__ __launch_bounds__(256) void gemm128_bt(
    const u16* __restrict__ A, const u16* __restrict__ Bt,
    float* __restrict__ outA, float* __restrict__ outB,
    int split, int ldA, int ldB, int K)
{
  __shared__ __align__(16) u16 As[128 * 32];
  __shared__ __align__(16) u16 Bs[128 * 32];
  const int tid  = threadIdx.x;
  const int lane = tid & 63;
  const int wid  = tid >> 6;
  const int m0 = blockIdx.y * 128;
  const int n0 = blockIdx.x * 128;
  const int wr = wid >> 1, wc = wid & 1;

  const f32x4 zero = {0.f, 0.f, 0.f, 0.f};
  f32x4 acc[4][4];
#pragma unroll
  for (int i = 0; i < 4; ++i)
#pragma unroll
    for (int j = 0; j < 4; ++j) acc[i][j] = zero;

  const int l16 = lane * 16;

  for (int k0 = 0; k0 < K; k0 += 32) {
    __syncthreads();   // previous iteration's LDS reads done
#pragma unroll
    for (int c = 0; c < 2; ++c) {
      const int base = c * 4096 + wid * 1024;     // wave-uniform LDS byte base
      const int ofs  = base + l16;                // this lane's dest byte
      const int row  = ofs >> 6;                  // 64 B per 32-elem bf16 row
      const int col  = (ofs >> 1) & 31;
      gload_lds16(A  + (size_t)(m0 + row) * K + k0 + col, (u16*)((char*)As + base));
      gload_lds16(Bt + (size_t)(n0 + row) * K + k0 + col, (u16*)((char*)Bs + base));
    }
    __syncthreads();   // staging complete (compiler drains vmcnt before barrier)

    const int kk = (lane >> 4) * 8;
    const int ra = wr * 64 + (lane & 15);
    const int rb = wc * 64 + (lane & 15);
    short8 af[4], bf[4];
#pragma unroll
    for (int i = 0; i < 4; ++i) af[i] = *(const short8*)&As[(ra + i * 16) * 32 + kk];
#pragma unroll
    for (int j = 0; j < 4; ++j) bf[j] = *(const short8*)&Bs[(rb + j * 16) * 32 + kk];
#pragma unroll
    for (int i = 0; i < 4; ++i)
#pragma unroll
      for (int j = 0; j < 4; ++j)
        acc[i][j] = __builtin_amdgcn_mfma_f32_16x16x32_bf16(af[i], bf[j], acc[i][j], 0, 0, 0);
  }

  // epilogue: C/D map col=lane&15, row=(lane>>4)*4+reg  [m89-verified]
  const int cr = (lane >> 4) * 4;
  const int cc = lane & 15;
#pragma unroll
  for (int i = 0; i < 4; ++i)
#pragma unroll
    for (int j = 0; j < 4; ++j)
#pragma unroll
      for (int r = 0; r < 4; ++r) {
        const int m = m0 + wr * 64 + i * 16 + cr + r;
        const int n = n0 + wc * 64 + j * 16 + cc;
        const float v = acc[i][j][r];
        if (n < split) outA[(size_t)m * ldA + n] = v;
        else           outB[(size_t)m * ldB + (n - split)] = v;
      }
}

// ---------------- small-N GEMM: one wave per 16x16 tile (x_proj) ----------------
__global__ __launch_bounds__(256) void gemm_wave16_bt(
    const u16* __restrict__ A, const u16* __restrict__ Bt,
    float* __restrict__ C, int M, int N, int K)
{
  const int wg   = blockIdx.x * 4 + (threadIdx.x >> 6);
  const int lane = threadIdx.x & 63;
  const int ntiles = N / 16;
  const int mt = wg / ntiles, nt = wg % ntiles;
  if (mt * 16 >= M) return;

  const u16* arow = A  + (size_t)(mt * 16 + (lane & 15)) * K + ((lane >> 4) * 8);
  const u16* brow = Bt + (size_t)(nt * 16 + (lane & 15)) * K + ((lane >> 4) * 8);
  f32x4 acc = {0.f, 0.f, 0.f, 0.f};
  for (int k0 = 0; k0 < K; k0 += 32) {
    short8 a = *(const short8*)(arow + k0);
    short8 b = *(const short8*)(brow + k0);
    acc = __builtin_amdgcn_mfma_f32_16x16x32_bf16(a, b, acc, 0, 0, 0);
  }
  const int cr = (lane >> 4) * 4, cc = lane & 15;
#pragma unroll
  for (int r = 0; r < 4; ++r)
    C[(size_t)(mt * 16 + cr + r) * N + nt * 16 + cc] = acc[r];
}

// ---------------- causal depthwise conv (W=4) + bias + SiLU ----------------
__global__ void conv_silu_kernel(const float* __restrict__ x,
                                 const float* __restrict__ cw, const float* __restrict__ cb,
                                 float* __restrict__ uf, u16* __restrict__ ub)
{
  const int idx = blockIdx.x * blockDim.x + threadIdx.x;   // over BL*DI
  if (idx >= BL * DI) return;
  const int d  = idx & (DI - 1);
  const int bl = idx >> 11;            // DI = 2048
  const int l  = bl & (Lseq - 1);      // Lseq = 2048
  const float4 w = *(const float4*)(cw + d * 4);
  float acc = cb[d];
  const float* xp = x + (size_t)bl * DI + d;
  const float x0 = (l >= 3) ? xp[-3 * DI] : 0.f;
  const float x1 = (l >= 2) ? xp[-2 * DI] : 0.f;
  const float x2 = (l >= 1) ? xp[-1 * DI] : 0.f;
  const float x3 = xp[0];
  acc += x0 * w.x + x1 * w.y + x2 * w.z + x3 * w.w;
  const float s = acc / (1.f + __expf(-acc));   // SiLU
  uf[idx] = s;
  ub[idx] = f32_to_bf16(s);
}

// ---------------- dt GEMM (K=64) in f32 + softplus ----------------
__global__ __launch_bounds__(256) void dt_gemm_kernel(
    const float* __restrict__ xdbl, const float* __restrict__ dtw,
    const float* __restrict__ dtb, float* __restrict__ delta)
{
  __shared__ __align__(16) float lds_dt[16 * 64];
  const int tid = threadIdx.x;
  const int m0 = blockIdx.y * 16;
  const int n  = blockIdx.x * 256 + tid;
  {
    const int e = tid * 4;
    const int mm = e >> 6, r = e & 63;
    *(float4*)&lds_dt[e] = *(const float4*)&xdbl[(size_t)(m0 + mm) * 96 + r];
  }
  __syncthreads();

  float acc[16];
#pragma unroll
  for (int mm = 0; mm < 16; ++mm) acc[mm] = 0.f;
  const float4* wrow = (const float4*)(dtw + (size_t)n * 64);
#pragma unroll
  for (int rb = 0; rb < 16; ++rb) {
    const float4 w4 = wrow[rb];
#pragma unroll
    for (int mm = 0; mm < 16; ++mm) {
      const float4 a = *(const float4*)&lds_dt[mm * 64 + rb * 4];
      acc[mm] += a.x * w4.x + a.y * w4.y + a.z * w4.z + a.w * w4.w;
    }
  }
  const float b = dtb[n];
#pragma unroll
  for (int mm = 0; mm < 16; ++mm) {
    const float v  = acc[mm] + b;
    const float sp = (v > 20.f) ? v : log1pf(__expf(v));   // softplus
    delta[(size_t)(m0 + mm) * DI + n] = sp;
  }
}

// ---------------- selective scan + skip + gate, writes gated y as bf16 ----------------
// thread layout: n = tid&15 (state), dd = tid>>4 (channel within block's 16 channels)
__global__ __launch_bounds__(256) void scan_kernel(
    const float* __restrict__ delta, const float* __restrict__ u,
    const float* __restrict__ xdbl, const float* __restrict__ alog,
    const float* __restrict__ dpar, const float* __restrict__ z,
    u16* __restrict__ yb)
{
  const int b   = blockIdx.y;
  const int d0  = blockIdx.x * 16;
  const int tid = threadIdx.x;
  const int n   = tid & 15;
  const int dd  = tid >> 4;
  const int d   = d0 + dd;

  const float A  = -__expf(alog[d * NS + n]);
  const float Dv = dpar[d];
  float h = 0.f;
  const size_t rowBase = (size_t)b * Lseq;

#pragma unroll 2
  for (int t = 0; t < Lseq; ++t) {
    const size_t row = rowBase + t;
    const float dt = delta[row * DI + d];
    const float ut = u[row * DI + d];
    const float Bn = xdbl[row * 96 + RR + n];
    const float Cn = xdbl[row * 96 + RR + NS + n];
    const float dA  = __expf(dt * A);
    const float dBu = dt * ut * Bn;
    h = dA * h + dBu;
    float yp = h * Cn;
    yp += __shfl_xor(yp, 1, 64);
    yp += __shfl_xor(yp, 2, 64);
    yp += __shfl_xor(yp, 4, 64);
    yp += __shfl_xor(yp, 8, 64);
    if (n == 0) {
      const float yv = yp + ut * Dv;
      const float zv = z[row * DI + d];
      const float g  = zv / (1.f + __expf(-zv));   // z * sigmoid(z)
      yb[row * DI + d] = f32_to_bf16(yv * g);
    }
  }
}

// ---------------- host launcher ----------------
extern "C" void kernel_launch(void* const* d_in, const int* in_sizes, int n_in,
                              void* d_out, int out_size, void* d_ws, size_t ws_size,
                              hipStream_t stream)
{
  const float* hs   = (const float*)d_in[0];  // (B,L,DM)
  const float* win  = (const float*)d_in[1];  // (2*DI, DM)
  const float* cw   = (const float*)d_in[2];  // (DI, 4)
  const float* cb   = (const float*)d_in[3];  // (DI,)
  const float* wxp  = (const float*)d_in[4];  // (96, DI)
  const float* wdt  = (const float*)d_in[5];  // (DI, 64)
  const float* bdt  = (const float*)d_in[6];  // (DI,)
  const float* alog = (const float*)d_in[7];  // (DI, NS)
  const float* dpar = (const float*)d_in[8];  // (DI,)
  const float* wout = (const float*)d_in[9];  // (DM, DI)
  float* out = (float*)d_out;                 // (B,L,DM) f32

  char* ws = (char*)d_ws;
  size_t off = 0;
  auto alloc = [&](size_t bytes) -> void* {
    void* p = ws + off;
    off += (bytes + 255) & ~(size_t)255;
    return p;
  };
  u16*   hs_b   = (u16*)  alloc((size_t)BL * DM * 2);        // 8 MB
  u16*   win_b  = (u16*)  alloc((size_t)2 * DI * DM * 2);    // 8 MB
  u16*   wxp_b  = (u16*)  alloc((size_t)96 * DI * 2);        // 0.4 MB
  u16*   wout_b = (u16*)  alloc((size_t)DM * DI * 2);        // 4 MB
  float* xbuf   = (float*)alloc((size_t)BL * DI * 4);        // 32 MB
  float* zbuf   = (float*)alloc((size_t)BL * DI * 4);        // 32 MB
  float* ubuf   = (float*)alloc((size_t)BL * DI * 4);        // 32 MB
  u16*   ub16   = (u16*)  alloc((size_t)BL * DI * 2);        // 16 MB
  float* xdbl   = (float*)alloc((size_t)BL * 96 * 4);        // 1.5 MB
  float* deltab = xbuf;   // reuse: x consumed by conv before dt_gemm writes delta
  u16*   y_b    = ub16;   // reuse: u_bf16 consumed by gemm_wave16 before scan writes y

  const int thr = 256;
  cvt_f32_bf16<<<(BL * DM / 4 + thr - 1) / thr, thr, 0, stream>>>(hs, hs_b, BL * DM);
  cvt_f32_bf16<<<(2 * DI * DM / 4 + thr - 1) / thr, thr, 0, stream>>>(win, win_b, 2 * DI * DM);
  cvt_f32_bf16<<<(96 * DI / 4 + thr - 1) / thr, thr, 0, stream>>>(wxp, wxp_b, 96 * DI);
  cvt_f32_bf16<<<(DM * DI / 4 + thr - 1) / thr, thr, 0, stream>>>(wout, wout_b, DM * DI);

  // GEMM1: xz = hs @ in_proj_w^T   (M=4096, N=4096, K=1024), split cols into x | z
  {
    dim3 g(4096 / 128, BL / 128);
    gemm128_bt<<<g, 256, 0, stream>>>(hs_b, win_b, xbuf, zbuf, DI, DI, DI, DM);
  }

  // conv + SiLU -> u (f32 + bf16)
  conv_silu_kernel<<<(BL * DI) / 256, 256, 0, stream>>>(xbuf, cw, cb, ubuf, ub16);

  // GEMM2: x_dbl = u @ x_proj_w^T  (M=4096, N=96, K=2048)
  gemm_wave16_bt<<<(BL / 16) * (96 / 16) / 4, 256, 0, stream>>>(ub16, wxp_b, xdbl, BL, 96, DI);

  // GEMM3 (f32): delta = softplus(dt_lo @ dt_proj_w^T + b)
  {
    dim3 g(DI / 256, BL / 16);
    dt_gemm_kernel<<<g, 256, 0, stream>>>(xdbl, wdt, bdt, deltab);
  }

  // selective scan + skip + gate -> y_bf16
  {
    dim3 g(DI / 16, Bsz);
    scan_kernel<<<g, 256, 0, stream>>>(deltab, ubuf, xdbl, alog, dpar, zbuf, y_b);
  }

  // GEMM4: out = y @ out_proj_w^T  (M=4096, N=1024, K=2048) -> d_out f32
  {
    dim3 g(DM / 128, BL / 128);
    gemm128_bt<<<g, 256, 0, stream>>>(y_b, wout_b, out, out, DM, DM, DM, DI);
  }
}

// Round 2
// 921.969 us; speedup vs baseline: 2.4484x; 2.4484x over previous
//
#include <hip/hip_runtime.h>
#include <cstdint>
#include <cstddef>

// ---- problem constants ----
#define Bsz  2
#define Lseq 2048
#define DM   1024
#define DI   2048
#define NS   16
#define RR   64
#define BL   (Bsz * Lseq)   // 4096 rows
#define TC   64             // scan chunk length
#define NC   (Lseq / TC)    // 32 chunks

typedef unsigned short u16;
typedef __attribute__((ext_vector_type(8))) short short8;   // 8 bf16 (4 VGPRs)
typedef __attribute__((ext_vector_type(4))) float f32x4;    // 4 f32 acc

__device__ __forceinline__ u16 f32_to_bf16(float f) {
  union { float f; unsigned int u; } v; v.f = f;
  unsigned int lsb = (v.u >> 16) & 1u;
  v.u += 0x7fffu + lsb;           // round-to-nearest-even
  return (u16)(v.u >> 16);
}

// ---------------- f32 -> bf16 conversion ----------------
__global__ void cvt_f32_bf16(const float* __restrict__ src, u16* __restrict__ dst, int n) {
  int i = (blockIdx.x * blockDim.x + threadIdx.x) * 4;
  if (i + 4 <= n) {
    float4 v = *(const float4*)(src + i);
    dst[i + 0] = f32_to_bf16(v.x);
    dst[i + 1] = f32_to_bf16(v.y);
    dst[i + 2] = f32_to_bf16(v.z);
    dst[i + 3] = f32_to_bf16(v.w);
  } else {
    for (; i < n; ++i) dst[i] = f32_to_bf16(src[i]);
  }
}

// ---------------- 128x128-tile bf16 MFMA GEMM (m97 structure) ----------------
__device__ __forceinline__ void gload_lds16(const u16* g, u16* l) {
  __builtin_amdgcn_global_load_lds(
      (const __attribute__((address_space(1))) unsigned int*)g,
      (__attribute__((address_space(3))) unsigned int*)l,
      16, 0, 0);
}

__global__ __launch_bounds__(256) void gemm128_bt(
    const u16* __restrict__ A, const u16* __restrict__ Bt,
    float* __restrict__ outA, float* __restrict__ outB,
    int split, int ldA, int ldB, int K)
{
  __shared__ __align__(16) u16 As[128 * 32];
  __shared__ __align__(16) u16 Bs[128 * 32];
  const int tid  = threadIdx.x;
  const int lane = tid & 63;
  const int wid  = tid >> 6;
  const int m0 = blockIdx.y * 128;
  const int n0 = blockIdx.x * 128;
  const int wr = wid >> 1, wc = wid & 1;

  const f32x4 zero = {0.f, 0.f, 0.f, 0.f};
  f32x4 acc[4][4];
#pragma unroll
  for (int i = 0; i < 4; ++i)
#pragma unroll
    for (int j = 0; j < 4; ++j) acc[i][j] = zero;

  const int l16 = lane * 16;

  for (int k0 = 0; k0 < K; k0 += 32) {
    __syncthreads();
#pragma unroll
    for (int c = 0; c < 2; ++c) {
      const int base = c * 4096 + wid * 1024;
      const int ofs  = base + l16;
      const int row  = ofs >> 6;
      const int col  = (ofs >> 1) & 31;
      gload_lds16(A  + (size_t)(m0 + row) * K + k0 + col, (u16*)((char*)As + base));
      gload_lds16(Bt + (size_t)(n0 + row) * K + k0 + col, (u16*)((char*)Bs + base));
    }
    __syncthreads();

    const int kk = (lane >> 4) * 8;
    const int ra = wr * 64 + (lane & 15);
    const int rb = wc * 64 + (lane & 15);
    short8 af[4], bf[4];
#pragma unroll
    for (int i = 0; i < 4; ++i) af[i] = *(const short8*)&As[(ra + i * 16) * 32 + kk];
#pragma unroll
    for (int j = 0; j < 4; ++j) bf[j] = *(const short8*)&Bs[(rb + j * 16) * 32 + kk];
#pragma unroll
    for (int i = 0; i < 4; ++i)
#pragma unroll
      for (int j = 0; j < 4; ++j)
        acc[i][j] = __builtin_amdgcn_mfma_f32_16x16x32_bf16(af[i], bf[j], acc[i][j], 0, 0, 0);
  }

  const int cr = (lane >> 4) * 4;
  const int cc = lane & 15;
#pragma unroll
  for (int i = 0; i < 4; ++i)
#pragma unroll
    for (int j = 0; j < 4; ++j)
#pragma unroll
      for (int r = 0; r < 4; ++r) {
        const int m = m0 + wr * 64 + i * 16 + cr + r;
        const int n = n0 + wc * 64 + j * 16 + cc;
        const float v = acc[i][j][r];
        if (n < split) outA[(size_t)m * ldA + n] = v;
        else           outB[(size_t)m * ldB + (n - split)] = v;
      }
}

// ---------------- small-N GEMM: one wave per 16x16 tile (x_proj) ----------------
__global__ __launch_bounds__(256) void gemm_wave16_bt(
    const u16* __restrict__ A, const u16* __restrict__ Bt,
    float* __restrict__ C, int M, int N, int K)
{
  const int wg   = blockIdx.x * 4 + (threadIdx.x >> 6);
  const int lane = threadIdx.x & 63;
  const int ntiles = N / 16;
  const int mt = wg / ntiles, nt = wg % ntiles;
  if (mt * 16 >= M) return;

  const u16* arow = A  + (size_t)(mt * 16 + (lane & 15)) * K + ((lane >> 4) * 8);
  const u16* brow = Bt + (size_t)(nt * 16 + (lane & 15)) * K + ((lane >> 4) * 8);
  f32x4 acc = {0.f, 0.f, 0.f, 0.f};
  for (int k0 = 0; k0 < K; k0 += 32) {
    short8 a = *(const short8*)(arow + k0);
    short8 b = *(const short8*)(brow + k0);
    acc = __builtin_amdgcn_mfma_f32_16x16x32_bf16(a, b, acc, 0, 0, 0);
  }
  const int cr = (lane >> 4) * 4, cc = lane & 15;
#pragma unroll
  for (int r = 0; r < 4; ++r)
    C[(size_t)(mt * 16 + cr + r) * N + nt * 16 + cc] = acc[r];
}

// ---------------- causal depthwise conv (W=4) + bias + SiLU ----------------
__global__ void conv_silu_kernel(const float* __restrict__ x,
                                 const float* __restrict__ cw, const float* __restrict__ cb,
                                 float* __restrict__ uf, u16* __restrict__ ub)
{
  const int idx = blockIdx.x * blockDim.x + threadIdx.x;   // over BL*DI
  if (idx >= BL * DI) return;
  const int d  = idx & (DI - 1);
  const int bl = idx >> 11;            // DI = 2048
  const int l  = bl & (Lseq - 1);      // Lseq = 2048
  const float4 w = *(const float4*)(cw + d * 4);
  float acc = cb[d];
  const float* xp = x + (size_t)bl * DI + d;
  const float x0 = (l >= 3) ? xp[-3 * DI] : 0.f;
  const float x1 = (l >= 2) ? xp[-2 * DI] : 0.f;
  const float x2 = (l >= 1) ? xp[-1 * DI] : 0.f;
  const float x3 = xp[0];
  acc += x0 * w.x + x1 * w.y + x2 * w.z + x3 * w.w;
  const float s = acc / (1.f + __expf(-acc));   // SiLU
  uf[idx] = s;
  ub[idx] = f32_to_bf16(s);
}

// ---------------- dt GEMM (K=64) in f32 + softplus ----------------
__global__ __launch_bounds__(256) void dt_gemm_kernel(
    const float* __restrict__ xdbl, const float* __restrict__ dtw,
    const float* __restrict__ dtb, float* __restrict__ delta)
{
  __shared__ __align__(16) float lds_dt[16 * 64];
  const int tid = threadIdx.x;
  const int m0 = blockIdx.y * 16;
  const int n  = blockIdx.x * 256 + tid;
  {
    const int e = tid * 4;
    const int mm = e >> 6, r = e & 63;
    *(float4*)&lds_dt[e] = *(const float4*)&xdbl[(size_t)(m0 + mm) * 96 + r];
  }
  __syncthreads();

  float acc[16];
#pragma unroll
  for (int mm = 0; mm < 16; ++mm) acc[mm] = 0.f;
  const float4* wrow = (const float4*)(dtw + (size_t)n * 64);
#pragma unroll
  for (int rb = 0; rb < 16; ++rb) {
    const float4 w4 = wrow[rb];
#pragma unroll
    for (int mm = 0; mm < 16; ++mm) {
      const float4 a = *(const float4*)&lds_dt[mm * 64 + rb * 4];
      acc[mm] += a.x * w4.x + a.y * w4.y + a.z * w4.z + a.w * w4.w;
    }
  }
  const float b = dtb[n];
#pragma unroll
  for (int mm = 0; mm < 16; ++mm) {
    const float v  = acc[mm] + b;
    const float sp = (v > 20.f) ? v : log1pf(__expf(v));   // softplus
    delta[(size_t)(m0 + mm) * DI + n] = sp;
  }
}

// ================= chunked selective scan =================
// recurrence h[t] = dA[t]*h[t-1] + dBu[t] is a diagonal linear recurrence:
//  A) per chunk c (T=64): P = prod dA, S = local state from h=0
//  B) h_in[c] = P[c-1]*h_in[c-1] + S[c-1]   (serial over NC=32 only)
//  C) re-run chunk from h_in, produce y (+skip, *gate) -> bf16

// ---- Kernel A: chunk-local products/partials ----
__global__ __launch_bounds__(256) void scan_chunk_ps(
    const float* __restrict__ delta, const float* __restrict__ u,
    const float* __restrict__ xdbl, const float* __restrict__ alog,
    float* __restrict__ Pout, float* __restrict__ Sout)
{
  __shared__ float dl[TC][16], ul[TC][16], Bl[TC][16];
  const int b   = blockIdx.z;
  const int c   = blockIdx.y;
  const int d0  = blockIdx.x * 16;
  const int tid = threadIdx.x;
  const int n   = tid & 15;
  const int dd  = tid >> 4;
  const int d   = d0 + dd;
  const size_t rowBase = (size_t)b * Lseq + (size_t)c * TC;

  {
    const int row = tid >> 2, c4 = (tid & 3) * 4;
    *(float4*)&dl[row][c4] = *(const float4*)&delta[(rowBase + row) * DI + d0 + c4];
    *(float4*)&ul[row][c4] = *(const float4*)&u[(rowBase + row) * DI + d0 + c4];
    *(float4*)&Bl[row][c4] = *(const float4*)&xdbl[(rowBase + row) * 96 + RR + c4];
  }
  __syncthreads();

  const float A = -__expf(alog[d * NS + n]);
  float h = 0.f, P = 1.f;
#pragma unroll 8
  for (int t = 0; t < TC; ++t) {
    const float dt = dl[t][dd];
    const float dA = __expf(dt * A);
    P *= dA;
    h  = dA * h + dt * ul[t][dd] * Bl[t][n];
  }
  const size_t o = ((size_t)(b * NC + c) * DI + d0) * NS + tid;
  Pout[o] = P;
  Sout[o] = h;
}

// ---- Kernel B: inter-chunk combine (serial over NC only) ----
__global__ __launch_bounds__(256) void scan_combine(
    const float* __restrict__ P, const float* __restrict__ S,
    float* __restrict__ Hin)   // may alias P (per-thread read-before-write)
{
  const int gid = blockIdx.x * 256 + threadIdx.x;  // over Bsz*DI*NS = 65536
  const int b   = gid >> 15;                       // DI*NS = 32768
  const int dn  = gid & 32767;
  float h = 0.f;
  for (int c = 0; c < NC; ++c) {
    const size_t o = ((size_t)(b * NC + c)) * (DI * NS) + dn;
    const float Pc = P[o];
    const float Sc = S[o];
    Hin[o] = h;
    h = Pc * h + Sc;
  }
}

// ---- Kernel C: chunk-local y with seeded state, + skip + gate -> bf16 ----
__global__ __launch_bounds__(256) void scan_chunk_y(
    const float* __restrict__ delta, const float* __restrict__ u,
    const float* __restrict__ xdbl, const float* __restrict__ alog,
    const float* __restrict__ dpar, const float* __restrict__ z,
    const float* __restrict__ Hin, u16* __restrict__ yb)
{
  __shared__ float dl[TC][16], ul[TC][16], Bl[TC][16], Cl[TC][16];
  const int b   = blockIdx.z;
  const int c   = blockIdx.y;
  const int d0  = blockIdx.x * 16;
  const int tid = threadIdx.x;
  const int n   = tid & 15;
  const int dd  = tid >> 4;
  const int d   = d0 + dd;
  const size_t rowBase = (size_t)b * Lseq + (size_t)c * TC;

  {
    const int row = tid >> 2, c4 = (tid & 3) * 4;
    *(float4*)&dl[row][c4] = *(const float4*)&delta[(rowBase + row) * DI + d0 + c4];
    *(float4*)&ul[row][c4] = *(const float4*)&u[(rowBase + row) * DI + d0 + c4];
    *(float4*)&Bl[row][c4] = *(const float4*)&xdbl[(rowBase + row) * 96 + RR + c4];
    *(float4*)&Cl[row][c4] = *(const float4*)&xdbl[(rowBase + row) * 96 + RR + NS + c4];
  }
  __syncthreads();

  const float A  = -__expf(alog[d * NS + n]);
  const float Dv = dpar[d];
  float h = Hin[((size_t)(b * NC + c) * DI + d0) * NS + tid];

#pragma unroll 4
  for (int t = 0; t < TC; ++t) {
    const float dt = dl[t][dd];
    const float ut = ul[t][dd];
    const float dA = __expf(dt * A);
    h = dA * h + dt * ut * Bl[t][n];
    float yp = h * Cl[t][n];
    yp += __shfl_xor(yp, 1, 64);
    yp += __shfl_xor(yp, 2, 64);
    yp += __shfl_xor(yp, 4, 64);
    yp += __shfl_xor(yp, 8, 64);
    if (n == 0) ul[t][dd] = yp + ut * Dv;   // same-wave group: all lanes already read ul[t][dd]
  }
  __syncthreads();

  // coalesced gated bf16 writeback
#pragma unroll
  for (int k = 0; k < 4; ++k) {
    const int idx = tid + k * 256;        // over TC*16 = 1024
    const int t   = idx >> 4;
    const int dx  = idx & 15;
    const float yv = ul[t][dx];
    const float zv = z[(rowBase + t) * DI + d0 + dx];
    const float g  = zv / (1.f + __expf(-zv));   // z * sigmoid(z)
    yb[(rowBase + t) * DI + d0 + dx] = f32_to_bf16(yv * g);
  }
}

// ---------------- host launcher ----------------
extern "C" void kernel_launch(void* const* d_in, const int* in_sizes, int n_in,
                              void* d_out, int out_size, void* d_ws, size_t ws_size,
                              hipStream_t stream)
{
  const float* hs   = (const float*)d_in[0];  // (B,L,DM)
  const float* win  = (const float*)d_in[1];  // (2*DI, DM)
  const float* cw   = (const float*)d_in[2];  // (DI, 4)
  const float* cb   = (const float*)d_in[3];  // (DI,)
  const float* wxp  = (const float*)d_in[4];  // (96, DI)
  const float* wdt  = (const float*)d_in[5];  // (DI, 64)
  const float* bdt  = (const float*)d_in[6];  // (DI,)
  const float* alog = (const float*)d_in[7];  // (DI, NS)
  const float* dpar = (const float*)d_in[8];  // (DI,)
  const float* wout = (const float*)d_in[9];  // (DM, DI)
  float* out = (float*)d_out;                 // (B,L,DM) f32

  char* ws = (char*)d_ws;
  size_t off = 0;
  auto alloc = [&](size_t bytes) -> void* {
    void* p = ws + off;
    off += (bytes + 255) & ~(size_t)255;
    return p;
  };
  u16*   hs_b   = (u16*)  alloc((size_t)BL * DM * 2);        // 8 MB
  u16*   win_b  = (u16*)  alloc((size_t)2 * DI * DM * 2);    // 8 MB
  u16*   wxp_b  = (u16*)  alloc((size_t)96 * DI * 2);        // 0.4 MB
  u16*   wout_b = (u16*)  alloc((size_t)DM * DI * 2);        // 4 MB
  float* xbuf   = (float*)alloc((size_t)BL * DI * 4);        // 32 MB
  float* zbuf   = (float*)alloc((size_t)BL * DI * 4);        // 32 MB
  float* ubuf   = (float*)alloc((size_t)BL * DI * 4);        // 32 MB
  u16*   ub16   = (u16*)  alloc((size_t)BL * DI * 2);        // 16 MB
  float* xdbl   = (float*)alloc((size_t)BL * 96 * 4);        // 1.5 MB
  float* Pbuf   = (float*)alloc((size_t)Bsz * NC * DI * NS * 4);  // 8.4 MB
  float* Sbuf   = (float*)alloc((size_t)Bsz * NC * DI * NS * 4);  // 8.4 MB
  float* deltab = xbuf;   // reuse: x consumed by conv before dt_gemm writes delta
  u16*   y_b    = ub16;   // reuse: u_bf16 consumed by gemm_wave16 before scan writes y
  float* Hin    = Pbuf;   // alias: scan_combine does per-thread read-P-then-write-Hin

  const int thr = 256;
  cvt_f32_bf16<<<(BL * DM / 4 + thr - 1) / thr, thr, 0, stream>>>(hs, hs_b, BL * DM);
  cvt_f32_bf16<<<(2 * DI * DM / 4 + thr - 1) / thr, thr, 0, stream>>>(win, win_b, 2 * DI * DM);
  cvt_f32_bf16<<<(96 * DI / 4 + thr - 1) / thr, thr, 0, stream>>>(wxp, wxp_b, 96 * DI);
  cvt_f32_bf16<<<(DM * DI / 4 + thr - 1) / thr, thr, 0, stream>>>(wout, wout_b, DM * DI);

  // GEMM1: xz = hs @ in_proj_w^T   (M=4096, N=4096, K=1024), split cols into x | z
  {
    dim3 g(4096 / 128, BL / 128);
    gemm128_bt<<<g, 256, 0, stream>>>(hs_b, win_b, xbuf, zbuf, DI, DI, DI, DM);
  }

  // conv + SiLU -> u (f32 + bf16)
  conv_silu_kernel<<<(BL * DI) / 256, 256, 0, stream>>>(xbuf, cw, cb, ubuf, ub16);

  // GEMM2: x_dbl = u @ x_proj_w^T  (M=4096, N=96, K=2048)
  gemm_wave16_bt<<<(BL / 16) * (96 / 16) / 4, 256, 0, stream>>>(ub16, wxp_b, xdbl, BL, 96, DI);

  // GEMM3 (f32): delta = softplus(dt_lo @ dt_proj_w^T + b)
  {
    dim3 g(DI / 256, BL / 16);
    dt_gemm_kernel<<<g, 256, 0, stream>>>(xdbl, wdt, bdt, deltab);
  }

  // chunked selective scan
  {
    dim3 gA(DI / 16, NC, Bsz);
    scan_chunk_ps<<<gA, 256, 0, stream>>>(deltab, ubuf, xdbl, alog, Pbuf, Sbuf);
    scan_combine<<<(Bsz * DI * NS) / 256, 256, 0, stream>>>(Pbuf, Sbuf, Hin);
    scan_chunk_y<<<gA, 256, 0, stream>>>(deltab, ubuf, xdbl, alog, dpar, zbuf, Hin, y_b);
  }

  // GEMM4: out = y @ out_proj_w^T  (M=4096, N=1024, K=2048) -> d_out f32
  {
    dim3 g(DM / 128, BL / 128);
    gemm128_bt<<<g, 256, 0, stream>>>(y_b, wout_b, out, out, DM, DM, DM, DI);
  }
}

// Round 3
// 393.672 us; speedup vs baseline: 5.7341x; 2.3420x over previous
//
#include <hip/hip_runtime.h>
#include <cstdint>
#include <cstddef>

// ---- problem constants ----
#define Bsz  2
#define Lseq 2048
#define DM   1024
#define DI   2048
#define NS   16
#define RR   64
#define BL   (Bsz * Lseq)   // 4096 rows
#define TC   64             // scan chunk length
#define NC   (Lseq / TC)    // 32 chunks

typedef unsigned short u16;
typedef __attribute__((ext_vector_type(8))) short short8;   // 8 bf16 (4 VGPRs)
typedef __attribute__((ext_vector_type(4))) float f32x4;    // 4 f32 acc

__device__ __forceinline__ u16 f32_to_bf16(float f) {
  union { float f; unsigned int u; } v; v.f = f;
  unsigned int lsb = (v.u >> 16) & 1u;
  v.u += 0x7fffu + lsb;           // round-to-nearest-even
  return (u16)(v.u >> 16);
}

// ---------------- f32 -> bf16 conversion ----------------
__global__ void cvt_f32_bf16(const float* __restrict__ src, u16* __restrict__ dst, int n) {
  int i = (blockIdx.x * blockDim.x + threadIdx.x) * 4;
  if (i + 4 <= n) {
    float4 v = *(const float4*)(src + i);
    dst[i + 0] = f32_to_bf16(v.x);
    dst[i + 1] = f32_to_bf16(v.y);
    dst[i + 2] = f32_to_bf16(v.z);
    dst[i + 3] = f32_to_bf16(v.w);
  } else {
    for (; i < n; ++i) dst[i] = f32_to_bf16(src[i]);
  }
}

// ---------------- 128x128-tile bf16 MFMA GEMM (m97 structure) ----------------
__device__ __forceinline__ void gload_lds16(const u16* g, u16* l) {
  __builtin_amdgcn_global_load_lds(
      (const __attribute__((address_space(1))) unsigned int*)g,
      (__attribute__((address_space(3))) unsigned int*)l,
      16, 0, 0);
}

__global__ __launch_bounds__(256) void gemm128_bt(
    const u16* __restrict__ A, const u16* __restrict__ Bt,
    float* __restrict__ outA, float* __restrict__ outB,
    int split, int ldA, int ldB, int K)
{
  __shared__ __align__(16) u16 As[128 * 32];
  __shared__ __align__(16) u16 Bs[128 * 32];
  const int tid  = threadIdx.x;
  const int lane = tid & 63;
  const int wid  = tid >> 6;
  const int m0 = blockIdx.y * 128;
  const int n0 = blockIdx.x * 128;
  const int wr = wid >> 1, wc = wid & 1;

  const f32x4 zero = {0.f, 0.f, 0.f, 0.f};
  f32x4 acc[4][4];
#pragma unroll
  for (int i = 0; i < 4; ++i)
#pragma unroll
    for (int j = 0; j < 4; ++j) acc[i][j] = zero;

  const int l16 = lane * 16;

  for (int k0 = 0; k0 < K; k0 += 32) {
    __syncthreads();
#pragma unroll
    for (int c = 0; c < 2; ++c) {
      const int base = c * 4096 + wid * 1024;
      const int ofs  = base + l16;
      const int row  = ofs >> 6;
      const int col  = (ofs >> 1) & 31;
      gload_lds16(A  + (size_t)(m0 + row) * K + k0 + col, (u16*)((char*)As + base));
      gload_lds16(Bt + (size_t)(n0 + row) * K + k0 + col, (u16*)((char*)Bs + base));
    }
    __syncthreads();

    const int kk = (lane >> 4) * 8;
    const int ra = wr * 64 + (lane & 15);
    const int rb = wc * 64 + (lane & 15);
    short8 af[4], bf[4];
#pragma unroll
    for (int i = 0; i < 4; ++i) af[i] = *(const short8*)&As[(ra + i * 16) * 32 + kk];
#pragma unroll
    for (int j = 0; j < 4; ++j) bf[j] = *(const short8*)&Bs[(rb + j * 16) * 32 + kk];
#pragma unroll
    for (int i = 0; i < 4; ++i)
#pragma unroll
      for (int j = 0; j < 4; ++j)
        acc[i][j] = __builtin_amdgcn_mfma_f32_16x16x32_bf16(af[i], bf[j], acc[i][j], 0, 0, 0);
  }

  const int cr = (lane >> 4) * 4;
  const int cc = lane & 15;
#pragma unroll
  for (int i = 0; i < 4; ++i)
#pragma unroll
    for (int j = 0; j < 4; ++j)
#pragma unroll
      for (int r = 0; r < 4; ++r) {
        const int m = m0 + wr * 64 + i * 16 + cr + r;
        const int n = n0 + wc * 64 + j * 16 + cc;
        const float v = acc[i][j][r];
        if (n < split) outA[(size_t)m * ldA + n] = v;
        else           outB[(size_t)m * ldB + (n - split)] = v;
      }
}

// ---------------- small-N GEMM: one wave per 16x16 tile (x_proj) ----------------
__global__ __launch_bounds__(256) void gemm_wave16_bt(
    const u16* __restrict__ A, const u16* __restrict__ Bt,
    float* __restrict__ C, int M, int N, int K)
{
  const int wg   = blockIdx.x * 4 + (threadIdx.x >> 6);
  const int lane = threadIdx.x & 63;
  const int ntiles = N / 16;
  const int mt = wg / ntiles, nt = wg % ntiles;
  if (mt * 16 >= M) return;

  const u16* arow = A  + (size_t)(mt * 16 + (lane & 15)) * K + ((lane >> 4) * 8);
  const u16* brow = Bt + (size_t)(nt * 16 + (lane & 15)) * K + ((lane >> 4) * 8);
  f32x4 acc = {0.f, 0.f, 0.f, 0.f};
  for (int k0 = 0; k0 < K; k0 += 32) {
    short8 a = *(const short8*)(arow + k0);
    short8 b = *(const short8*)(brow + k0);
    acc = __builtin_amdgcn_mfma_f32_16x16x32_bf16(a, b, acc, 0, 0, 0);
  }
  const int cr = (lane >> 4) * 4, cc = lane & 15;
#pragma unroll
  for (int r = 0; r < 4; ++r)
    C[(size_t)(mt * 16 + cr + r) * N + nt * 16 + cc] = acc[r];
}

// ---------------- causal depthwise conv (W=4) + bias + SiLU ----------------
__global__ void conv_silu_kernel(const float* __restrict__ x,
                                 const float* __restrict__ cw, const float* __restrict__ cb,
                                 float* __restrict__ uf, u16* __restrict__ ub)
{
  const int idx = blockIdx.x * blockDim.x + threadIdx.x;   // over BL*DI
  if (idx >= BL * DI) return;
  const int d  = idx & (DI - 1);
  const int bl = idx >> 11;            // DI = 2048
  const int l  = bl & (Lseq - 1);      // Lseq = 2048
  const float4 w = *(const float4*)(cw + d * 4);
  float acc = cb[d];
  const float* xp = x + (size_t)bl * DI + d;
  const float x0 = (l >= 3) ? xp[-3 * DI] : 0.f;
  const float x1 = (l >= 2) ? xp[-2 * DI] : 0.f;
  const float x2 = (l >= 1) ? xp[-1 * DI] : 0.f;
  const float x3 = xp[0];
  acc += x0 * w.x + x1 * w.y + x2 * w.z + x3 * w.w;
  const float s = acc / (1.f + __expf(-acc));   // SiLU
  uf[idx] = s;
  ub[idx] = f32_to_bf16(s);
}

// ---------------- dt GEMM (K=64) in f32 + softplus ----------------
// Register-bounded rewrite: hoist the 16 dtw float4s (64 VGPRs), then one
// output row at a time (LDS reads are wave-uniform -> broadcast, no conflicts),
// softplus + store immediately (no acc array). Previous version double-unrolled
// rb x mm -> 256 VGPRs (cap) -> scratch spill -> 1.65 GB HBM traffic, 570 us.
__global__ __launch_bounds__(256) void dt_gemm_kernel(
    const float* __restrict__ xdbl, const float* __restrict__ dtw,
    const float* __restrict__ dtb, float* __restrict__ delta)
{
  __shared__ __align__(16) float lds_dt[16 * 64];
  const int tid = threadIdx.x;
  const int m0 = blockIdx.y * 16;
  const int n  = blockIdx.x * 256 + tid;
  {
    const int e = tid * 4;
    const int mm = e >> 6, r = e & 63;
    *(float4*)&lds_dt[e] = *(const float4*)&xdbl[(size_t)(m0 + mm) * 96 + r];
  }

  // hoist weights: 16 x float4 = 64 VGPRs, loads issue back-to-back (MLP)
  float4 w[16];
  const float4* wrow = (const float4*)(dtw + (size_t)n * 64);
#pragma unroll
  for (int rb = 0; rb < 16; ++rb) w[rb] = wrow[rb];
  const float b = dtb[n];

  __syncthreads();

#pragma unroll 1
  for (int mm = 0; mm < 16; ++mm) {
    float s = b;
#pragma unroll
    for (int rb = 0; rb < 16; ++rb) {
      const float4 a = *(const float4*)&lds_dt[mm * 64 + rb * 4];
      s += a.x * w[rb].x + a.y * w[rb].y + a.z * w[rb].z + a.w * w[rb].w;
    }
    const float sp = (s > 20.f) ? s : log1pf(__expf(s));   // softplus
    delta[(size_t)(m0 + mm) * DI + n] = sp;
  }
}

// ================= chunked selective scan =================
// recurrence h[t] = dA[t]*h[t-1] + dBu[t] is a diagonal linear recurrence:
//  A) per chunk c (T=64): P = prod dA, S = local state from h=0
//  B) h_in[c] = P[c-1]*h_in[c-1] + S[c-1]   (serial over NC=32 only)
//  C) re-run chunk from h_in, produce y (+skip, *gate) -> bf16

// ---- Kernel A: chunk-local products/partials ----
__global__ __launch_bounds__(256) void scan_chunk_ps(
    const float* __restrict__ delta, const float* __restrict__ u,
    const float* __restrict__ xdbl, const float* __restrict__ alog,
    float* __restrict__ Pout, float* __restrict__ Sout)
{
  __shared__ float dl[TC][16], ul[TC][16], Bl[TC][16];
  const int b   = blockIdx.z;
  const int c   = blockIdx.y;
  const int d0  = blockIdx.x * 16;
  const int tid = threadIdx.x;
  const int n   = tid & 15;
  const int dd  = tid >> 4;
  const int d   = d0 + dd;
  const size_t rowBase = (size_t)b * Lseq + (size_t)c * TC;

  {
    const int row = tid >> 2, c4 = (tid & 3) * 4;
    *(float4*)&dl[row][c4] = *(const float4*)&delta[(rowBase + row) * DI + d0 + c4];
    *(float4*)&ul[row][c4] = *(const float4*)&u[(rowBase + row) * DI + d0 + c4];
    *(float4*)&Bl[row][c4] = *(const float4*)&xdbl[(rowBase + row) * 96 + RR + c4];
  }
  __syncthreads();

  const float A = -__expf(alog[d * NS + n]);
  float h = 0.f, P = 1.f;
#pragma unroll 8
  for (int t = 0; t < TC; ++t) {
    const float dt = dl[t][dd];
    const float dA = __expf(dt * A);
    P *= dA;
    h  = dA * h + dt * ul[t][dd] * Bl[t][n];
  }
  const size_t o = ((size_t)(b * NC + c) * DI + d0) * NS + tid;
  Pout[o] = P;
  Sout[o] = h;
}

// ---- Kernel B: inter-chunk combine (serial over NC only) ----
__global__ __launch_bounds__(256) void scan_combine(
    const float* __restrict__ P, const float* __restrict__ S,
    float* __restrict__ Hin)   // may alias P (per-thread read-before-write)
{
  const int gid = blockIdx.x * 256 + threadIdx.x;  // over Bsz*DI*NS = 65536
  const int b   = gid >> 15;                       // DI*NS = 32768
  const int dn  = gid & 32767;
  float h = 0.f;
  for (int c = 0; c < NC; ++c) {
    const size_t o = ((size_t)(b * NC + c)) * (DI * NS) + dn;
    const float Pc = P[o];
    const float Sc = S[o];
    Hin[o] = h;
    h = Pc * h + Sc;
  }
}

// ---- Kernel C: chunk-local y with seeded state, + skip + gate -> bf16 ----
__global__ __launch_bounds__(256) void scan_chunk_y(
    const float* __restrict__ delta, const float* __restrict__ u,
    const float* __restrict__ xdbl, const float* __restrict__ alog,
    const float* __restrict__ dpar, const float* __restrict__ z,
    const float* __restrict__ Hin, u16* __restrict__ yb)
{
  __shared__ float dl[TC][16], ul[TC][16], Bl[TC][16], Cl[TC][16];
  const int b   = blockIdx.z;
  const int c   = blockIdx.y;
  const int d0  = blockIdx.x * 16;
  const int tid = threadIdx.x;
  const int n   = tid & 15;
  const int dd  = tid >> 4;
  const int d   = d0 + dd;
  const size_t rowBase = (size_t)b * Lseq + (size_t)c * TC;

  {
    const int row = tid >> 2, c4 = (tid & 3) * 4;
    *(float4*)&dl[row][c4] = *(const float4*)&delta[(rowBase + row) * DI + d0 + c4];
    *(float4*)&ul[row][c4] = *(const float4*)&u[(rowBase + row) * DI + d0 + c4];
    *(float4*)&Bl[row][c4] = *(const float4*)&xdbl[(rowBase + row) * 96 + RR + c4];
    *(float4*)&Cl[row][c4] = *(const float4*)&xdbl[(rowBase + row) * 96 + RR + NS + c4];
  }
  __syncthreads();

  const float A  = -__expf(alog[d * NS + n]);
  const float Dv = dpar[d];
  float h = Hin[((size_t)(b * NC + c) * DI + d0) * NS + tid];

#pragma unroll 4
  for (int t = 0; t < TC; ++t) {
    const float dt = dl[t][dd];
    const float ut = ul[t][dd];
    const float dA = __expf(dt * A);
    h = dA * h + dt * ut * Bl[t][n];
    float yp = h * Cl[t][n];
    yp += __shfl_xor(yp, 1, 64);
    yp += __shfl_xor(yp, 2, 64);
    yp += __shfl_xor(yp, 4, 64);
    yp += __shfl_xor(yp, 8, 64);
    if (n == 0) ul[t][dd] = yp + ut * Dv;   // same-wave group: all lanes already read ul[t][dd]
  }
  __syncthreads();

  // coalesced gated bf16 writeback
#pragma unroll
  for (int k = 0; k < 4; ++k) {
    const int idx = tid + k * 256;        // over TC*16 = 1024
    const int t   = idx >> 4;
    const int dx  = idx & 15;
    const float yv = ul[t][dx];
    const float zv = z[(rowBase + t) * DI + d0 + dx];
    const float g  = zv / (1.f + __expf(-zv));   // z * sigmoid(z)
    yb[(rowBase + t) * DI + d0 + dx] = f32_to_bf16(yv * g);
  }
}

// ---------------- host launcher ----------------
extern "C" void kernel_launch(void* const* d_in, const int* in_sizes, int n_in,
                              void* d_out, int out_size, void* d_ws, size_t ws_size,
                              hipStream_t stream)
{
  const float* hs   = (const float*)d_in[0];  // (B,L,DM)
  const float* win  = (const float*)d_in[1];  // (2*DI, DM)
  const float* cw   = (const float*)d_in[2];  // (DI, 4)
  const float* cb   = (const float*)d_in[3];  // (DI,)
  const float* wxp  = (const float*)d_in[4];  // (96, DI)
  const float* wdt  = (const float*)d_in[5];  // (DI, 64)
  const float* bdt  = (const float*)d_in[6];  // (DI,)
  const float* alog = (const float*)d_in[7];  // (DI, NS)
  const float* dpar = (const float*)d_in[8];  // (DI,)
  const float* wout = (const float*)d_in[9];  // (DM, DI)
  float* out = (float*)d_out;                 // (B,L,DM) f32

  char* ws = (char*)d_ws;
  size_t off = 0;
  auto alloc = [&](size_t bytes) -> void* {
    void* p = ws + off;
    off += (bytes + 255) & ~(size_t)255;
    return p;
  };
  u16*   hs_b   = (u16*)  alloc((size_t)BL * DM * 2);        // 8 MB
  u16*   win_b  = (u16*)  alloc((size_t)2 * DI * DM * 2);    // 8 MB
  u16*   wxp_b  = (u16*)  alloc((size_t)96 * DI * 2);        // 0.4 MB
  u16*   wout_b = (u16*)  alloc((size_t)DM * DI * 2);        // 4 MB
  float* xbuf   = (float*)alloc((size_t)BL * DI * 4);        // 32 MB
  float* zbuf   = (float*)alloc((size_t)BL * DI * 4);        // 32 MB
  float* ubuf   = (float*)alloc((size_t)BL * DI * 4);        // 32 MB
  u16*   ub16   = (u16*)  alloc((size_t)BL * DI * 2);        // 16 MB
  float* xdbl   = (float*)alloc((size_t)BL * 96 * 4);        // 1.5 MB
  float* Pbuf   = (float*)alloc((size_t)Bsz * NC * DI * NS * 4);  // 8.4 MB
  float* Sbuf   = (float*)alloc((size_t)Bsz * NC * DI * NS * 4);  // 8.4 MB
  float* deltab = xbuf;   // reuse: x consumed by conv before dt_gemm writes delta
  u16*   y_b    = ub16;   // reuse: u_bf16 consumed by gemm_wave16 before scan writes y
  float* Hin    = Pbuf;   // alias: scan_combine does per-thread read-P-then-write-Hin

  const int thr = 256;
  cvt_f32_bf16<<<(BL * DM / 4 + thr - 1) / thr, thr, 0, stream>>>(hs, hs_b, BL * DM);
  cvt_f32_bf16<<<(2 * DI * DM / 4 + thr - 1) / thr, thr, 0, stream>>>(win, win_b, 2 * DI * DM);
  cvt_f32_bf16<<<(96 * DI / 4 + thr - 1) / thr, thr, 0, stream>>>(wxp, wxp_b, 96 * DI);
  cvt_f32_bf16<<<(DM * DI / 4 + thr - 1) / thr, thr, 0, stream>>>(wout, wout_b, DM * DI);

  // GEMM1: xz = hs @ in_proj_w^T   (M=4096, N=4096, K=1024), split cols into x | z
  {
    dim3 g(4096 / 128, BL / 128);
    gemm128_bt<<<g, 256, 0, stream>>>(hs_b, win_b, xbuf, zbuf, DI, DI, DI, DM);
  }

  // conv + SiLU -> u (f32 + bf16)
  conv_silu_kernel<<<(BL * DI) / 256, 256, 0, stream>>>(xbuf, cw, cb, ubuf, ub16);

  // GEMM2: x_dbl = u @ x_proj_w^T  (M=4096, N=96, K=2048)
  gemm_wave16_bt<<<(BL / 16) * (96 / 16) / 4, 256, 0, stream>>>(ub16, wxp_b, xdbl, BL, 96, DI);

  // GEMM3 (f32): delta = softplus(dt_lo @ dt_proj_w^T + b)
  {
    dim3 g(DI / 256, BL / 16);
    dt_gemm_kernel<<<g, 256, 0, stream>>>(xdbl, wdt, bdt, deltab);
  }

  // chunked selective scan
  {
    dim3 gA(DI / 16, NC, Bsz);
    scan_chunk_ps<<<gA, 256, 0, stream>>>(deltab, ubuf, xdbl, alog, Pbuf, Sbuf);
    scan_combine<<<(Bsz * DI * NS) / 256, 256, 0, stream>>>(Pbuf, Sbuf, Hin);
    scan_chunk_y<<<gA, 256, 0, stream>>>(deltab, ubuf, xdbl, alog, dpar, zbuf, Hin, y_b);
  }

  // GEMM4: out = y @ out_proj_w^T  (M=4096, N=1024, K=2048) -> d_out f32
  {
    dim3 g(DM / 128, BL / 128);
    gemm128_bt<<<g, 256, 0, stream>>>(y_b, wout_b, out, out, DM, DM, DM, DI);
  }
}

// Round 4
// 312.430 us; speedup vs baseline: 7.2252x; 1.2600x over previous
//
#include <hip/hip_runtime.h>
#include <cstdint>
#include <cstddef>

// ---- problem constants ----
#define Bsz  2
#define Lseq 2048
#define DM   1024
#define DI   2048
#define NS   16
#define RR   64
#define BL   (Bsz * Lseq)   // 4096 rows
#define TC   64             // scan chunk length
#define NC   (Lseq / TC)    // 32 chunks

typedef unsigned short u16;
typedef __attribute__((ext_vector_type(8))) short short8;   // 8 bf16 (4 VGPRs)
typedef __attribute__((ext_vector_type(4))) float f32x4;    // 4 f32 acc

__device__ __forceinline__ u16 f32_to_bf16(float f) {
  union { float f; unsigned int u; } v; v.f = f;
  unsigned int lsb = (v.u >> 16) & 1u;
  v.u += 0x7fffu + lsb;           // round-to-nearest-even
  return (u16)(v.u >> 16);
}

// ---------------- f32 -> bf16 conversion ----------------
__global__ void cvt_f32_bf16(const float* __restrict__ src, u16* __restrict__ dst, int n) {
  int i = (blockIdx.x * blockDim.x + threadIdx.x) * 4;
  if (i + 4 <= n) {
    float4 v = *(const float4*)(src + i);
    dst[i + 0] = f32_to_bf16(v.x);
    dst[i + 1] = f32_to_bf16(v.y);
    dst[i + 2] = f32_to_bf16(v.z);
    dst[i + 3] = f32_to_bf16(v.w);
  } else {
    for (; i < n; ++i) dst[i] = f32_to_bf16(src[i]);
  }
}

// ---------------- 128x128-tile bf16 MFMA GEMM (m97 structure) ----------------
__device__ __forceinline__ void gload_lds16(const u16* g, u16* l) {
  __builtin_amdgcn_global_load_lds(
      (const __attribute__((address_space(1))) unsigned int*)g,
      (__attribute__((address_space(3))) unsigned int*)l,
      16, 0, 0);
}

__global__ __launch_bounds__(256) void gemm128_bt(
    const u16* __restrict__ A, const u16* __restrict__ Bt,
    float* __restrict__ outA, float* __restrict__ outB,
    int split, int ldA, int ldB, int K)
{
  __shared__ __align__(16) u16 As[128 * 32];
  __shared__ __align__(16) u16 Bs[128 * 32];
  const int tid  = threadIdx.x;
  const int lane = tid & 63;
  const int wid  = tid >> 6;
  const int m0 = blockIdx.y * 128;
  const int n0 = blockIdx.x * 128;
  const int wr = wid >> 1, wc = wid & 1;

  const f32x4 zero = {0.f, 0.f, 0.f, 0.f};
  f32x4 acc[4][4];
#pragma unroll
  for (int i = 0; i < 4; ++i)
#pragma unroll
    for (int j = 0; j < 4; ++j) acc[i][j] = zero;

  const int l16 = lane * 16;

  for (int k0 = 0; k0 < K; k0 += 32) {
    __syncthreads();
#pragma unroll
    for (int c = 0; c < 2; ++c) {
      const int base = c * 4096 + wid * 1024;
      const int ofs  = base + l16;
      const int row  = ofs >> 6;
      const int col  = (ofs >> 1) & 31;
      gload_lds16(A  + (size_t)(m0 + row) * K + k0 + col, (u16*)((char*)As + base));
      gload_lds16(Bt + (size_t)(n0 + row) * K + k0 + col, (u16*)((char*)Bs + base));
    }
    __syncthreads();

    const int kk = (lane >> 4) * 8;
    const int ra = wr * 64 + (lane & 15);
    const int rb = wc * 64 + (lane & 15);
    short8 af[4], bf[4];
#pragma unroll
    for (int i = 0; i < 4; ++i) af[i] = *(const short8*)&As[(ra + i * 16) * 32 + kk];
#pragma unroll
    for (int j = 0; j < 4; ++j) bf[j] = *(const short8*)&Bs[(rb + j * 16) * 32 + kk];
#pragma unroll
    for (int i = 0; i < 4; ++i)
#pragma unroll
      for (int j = 0; j < 4; ++j)
        acc[i][j] = __builtin_amdgcn_mfma_f32_16x16x32_bf16(af[i], bf[j], acc[i][j], 0, 0, 0);
  }

  const int cr = (lane >> 4) * 4;
  const int cc = lane & 15;
#pragma unroll
  for (int i = 0; i < 4; ++i)
#pragma unroll
    for (int j = 0; j < 4; ++j)
#pragma unroll
      for (int r = 0; r < 4; ++r) {
        const int m = m0 + wr * 64 + i * 16 + cr + r;
        const int n = n0 + wc * 64 + j * 16 + cc;
        const float v = acc[i][j][r];
        if (n < split) outA[(size_t)m * ldA + n] = v;
        else           outB[(size_t)m * ldB + (n - split)] = v;
      }
}

// ---------------- small-N GEMM: one wave per 16x16 tile (x_proj) ----------------
__global__ __launch_bounds__(256) void gemm_wave16_bt(
    const u16* __restrict__ A, const u16* __restrict__ Bt,
    float* __restrict__ C, int M, int N, int K)
{
  const int wg   = blockIdx.x * 4 + (threadIdx.x >> 6);
  const int lane = threadIdx.x & 63;
  const int ntiles = N / 16;
  const int mt = wg / ntiles, nt = wg % ntiles;
  if (mt * 16 >= M) return;

  const u16* arow = A  + (size_t)(mt * 16 + (lane & 15)) * K + ((lane >> 4) * 8);
  const u16* brow = Bt + (size_t)(nt * 16 + (lane & 15)) * K + ((lane >> 4) * 8);
  f32x4 acc = {0.f, 0.f, 0.f, 0.f};
  for (int k0 = 0; k0 < K; k0 += 32) {
    short8 a = *(const short8*)(arow + k0);
    short8 b = *(const short8*)(brow + k0);
    acc = __builtin_amdgcn_mfma_f32_16x16x32_bf16(a, b, acc, 0, 0, 0);
  }
  const int cr = (lane >> 4) * 4, cc = lane & 15;
#pragma unroll
  for (int r = 0; r < 4; ++r)
    C[(size_t)(mt * 16 + cr + r) * N + nt * 16 + cc] = acc[r];
}

// ---------------- causal depthwise conv (W=4) + bias + SiLU ----------------
__global__ void conv_silu_kernel(const float* __restrict__ x,
                                 const float* __restrict__ cw, const float* __restrict__ cb,
                                 float* __restrict__ uf, u16* __restrict__ ub)
{
  const int idx = blockIdx.x * blockDim.x + threadIdx.x;   // over BL*DI
  if (idx >= BL * DI) return;
  const int d  = idx & (DI - 1);
  const int bl = idx >> 11;            // DI = 2048
  const int l  = bl & (Lseq - 1);      // Lseq = 2048
  const float4 w = *(const float4*)(cw + d * 4);
  float acc = cb[d];
  const float* xp = x + (size_t)bl * DI + d;
  const float x0 = (l >= 3) ? xp[-3 * DI] : 0.f;
  const float x1 = (l >= 2) ? xp[-2 * DI] : 0.f;
  const float x2 = (l >= 1) ? xp[-1 * DI] : 0.f;
  const float x3 = xp[0];
  acc += x0 * w.x + x1 * w.y + x2 * w.z + x3 * w.w;
  const float s = acc / (1.f + __expf(-acc));   // SiLU
  uf[idx] = s;
  ub[idx] = f32_to_bf16(s);
}

// ---------------- dt GEMM (K=64) in f32 + softplus ----------------
// Register-bounded: hoist 16 dtw float4s, one output row at a time, no acc array.
__global__ __launch_bounds__(256) void dt_gemm_kernel(
    const float* __restrict__ xdbl, const float* __restrict__ dtw,
    const float* __restrict__ dtb, float* __restrict__ delta)
{
  __shared__ __align__(16) float lds_dt[16 * 64];
  const int tid = threadIdx.x;
  const int m0 = blockIdx.y * 16;
  const int n  = blockIdx.x * 256 + tid;
  {
    const int e = tid * 4;
    const int mm = e >> 6, r = e & 63;
    *(float4*)&lds_dt[e] = *(const float4*)&xdbl[(size_t)(m0 + mm) * 96 + r];
  }

  float4 w[16];
  const float4* wrow = (const float4*)(dtw + (size_t)n * 64);
#pragma unroll
  for (int rb = 0; rb < 16; ++rb) w[rb] = wrow[rb];
  const float b = dtb[n];

  __syncthreads();

#pragma unroll 1
  for (int mm = 0; mm < 16; ++mm) {
    float s = b;
#pragma unroll
    for (int rb = 0; rb < 16; ++rb) {
      const float4 a = *(const float4*)&lds_dt[mm * 64 + rb * 4];
      s += a.x * w[rb].x + a.y * w[rb].y + a.z * w[rb].z + a.w * w[rb].w;
    }
    const float sp = (s > 20.f) ? s : log1pf(__expf(s));   // softplus
    delta[(size_t)(m0 + mm) * DI + n] = sp;
  }
}

// ================= chunked selective scan =================
// Thread-owns-channel layout: each thread owns one d, holds all NS=16 states
// in VGPRs. n-reduction is 16 in-register FMAs -> zero cross-lane ops (the
// previous (n,dd) layout spent 4 dependent shfl_xor per t on an all-reduce).
// B/C tiles staged in LDS, read as broadcast (conflict-free).
// P/S/Hin layout: [(b*NC+c)*NS + n]*DI + d  (coalesced over d).

// ---- Kernel A: chunk-local products/partials ----
__global__ __launch_bounds__(256) void scan_chunk_ps(
    const float* __restrict__ delta, const float* __restrict__ u,
    const float* __restrict__ xdbl, const float* __restrict__ alog,
    float* __restrict__ Pout, float* __restrict__ Sout)
{
  __shared__ float Bl[TC][NS];
  const int b   = blockIdx.z;
  const int c   = blockIdx.y;
  const int d   = blockIdx.x * 256 + threadIdx.x;
  const int tid = threadIdx.x;
  const size_t rowBase = (size_t)b * Lseq + (size_t)c * TC;

  {
    const int row = tid >> 2, c4 = (tid & 3) * 4;
    *(float4*)&Bl[row][c4] = *(const float4*)&xdbl[(rowBase + row) * 96 + RR + c4];
  }
  __syncthreads();

  float A[NS];
#pragma unroll
  for (int n4 = 0; n4 < 4; ++n4) {
    const float4 a4 = *(const float4*)&alog[(size_t)d * NS + n4 * 4];
    A[n4 * 4 + 0] = -__expf(a4.x);
    A[n4 * 4 + 1] = -__expf(a4.y);
    A[n4 * 4 + 2] = -__expf(a4.z);
    A[n4 * 4 + 3] = -__expf(a4.w);
  }

  float h[NS], P[NS];
#pragma unroll
  for (int n = 0; n < NS; ++n) { h[n] = 0.f; P[n] = 1.f; }

#pragma unroll 4
  for (int t = 0; t < TC; ++t) {
    const float dt  = delta[(rowBase + t) * DI + d];
    const float ut  = u[(rowBase + t) * DI + d];
    const float dtu = dt * ut;
#pragma unroll
    for (int n = 0; n < NS; ++n) {
      const float dA = __expf(dt * A[n]);
      P[n] *= dA;
      h[n] = dA * h[n] + dtu * Bl[t][n];
    }
  }

  const size_t base = (size_t)(b * NC + c) * NS * DI + d;
#pragma unroll
  for (int n = 0; n < NS; ++n) {
    Pout[base + (size_t)n * DI] = P[n];
    Sout[base + (size_t)n * DI] = h[n];
  }
}

// ---- Kernel B: inter-chunk combine (serial over NC only) ----
__global__ __launch_bounds__(256) void scan_combine(
    const float* __restrict__ P, const float* __restrict__ S,
    float* __restrict__ Hin)   // may alias P (per-thread read-before-write)
{
  const int gid = blockIdx.x * 256 + threadIdx.x;  // over Bsz*NS*DI = 65536
  const int b   = gid >> 15;                       // NS*DI = 32768
  const int nd  = gid & 32767;
  float h = 0.f;
  for (int c = 0; c < NC; ++c) {
    const size_t o = (size_t)(b * NC + c) * (NS * DI) + nd;
    const float Pc = P[o];
    const float Sc = S[o];
    Hin[o] = h;
    h = Pc * h + Sc;
  }
}

// ---- Kernel C: chunk-local y with seeded state, + skip + gate -> bf16 ----
__global__ __launch_bounds__(256) void scan_chunk_y(
    const float* __restrict__ delta, const float* __restrict__ u,
    const float* __restrict__ xdbl, const float* __restrict__ alog,
    const float* __restrict__ dpar, const float* __restrict__ z,
    const float* __restrict__ Hin, u16* __restrict__ yb)
{
  __shared__ float Bl[TC][NS];
  __shared__ float Cl[TC][NS];
  const int b   = blockIdx.z;
  const int c   = blockIdx.y;
  const int d   = blockIdx.x * 256 + threadIdx.x;
  const int tid = threadIdx.x;
  const size_t rowBase = (size_t)b * Lseq + (size_t)c * TC;

  {
    const int row = tid >> 2, c4 = (tid & 3) * 4;
    *(float4*)&Bl[row][c4] = *(const float4*)&xdbl[(rowBase + row) * 96 + RR + c4];
    *(float4*)&Cl[row][c4] = *(const float4*)&xdbl[(rowBase + row) * 96 + RR + NS + c4];
  }
  __syncthreads();

  float A[NS];
#pragma unroll
  for (int n4 = 0; n4 < 4; ++n4) {
    const float4 a4 = *(const float4*)&alog[(size_t)d * NS + n4 * 4];
    A[n4 * 4 + 0] = -__expf(a4.x);
    A[n4 * 4 + 1] = -__expf(a4.y);
    A[n4 * 4 + 2] = -__expf(a4.z);
    A[n4 * 4 + 3] = -__expf(a4.w);
  }
  const float Dv = dpar[d];

  float h[NS];
  const size_t sbase = (size_t)(b * NC + c) * NS * DI + d;
#pragma unroll
  for (int n = 0; n < NS; ++n) h[n] = Hin[sbase + (size_t)n * DI];

#pragma unroll 4
  for (int t = 0; t < TC; ++t) {
    const float dt  = delta[(rowBase + t) * DI + d];
    const float ut  = u[(rowBase + t) * DI + d];
    const float zv  = z[(rowBase + t) * DI + d];
    const float dtu = dt * ut;
    float y = 0.f;
#pragma unroll
    for (int n = 0; n < NS; ++n) {
      const float dA = __expf(dt * A[n]);
      h[n] = dA * h[n] + dtu * Bl[t][n];
      y += h[n] * Cl[t][n];
    }
    const float yv = y + ut * Dv;
    const float g  = zv / (1.f + __expf(-zv));   // z * sigmoid(z)
    yb[(rowBase + t) * DI + d] = f32_to_bf16(yv * g);
  }
}

// ---------------- host launcher ----------------
extern "C" void kernel_launch(void* const* d_in, const int* in_sizes, int n_in,
                              void* d_out, int out_size, void* d_ws, size_t ws_size,
                              hipStream_t stream)
{
  const float* hs   = (const float*)d_in[0];  // (B,L,DM)
  const float* win  = (const float*)d_in[1];  // (2*DI, DM)
  const float* cw   = (const float*)d_in[2];  // (DI, 4)
  const float* cb   = (const float*)d_in[3];  // (DI,)
  const float* wxp  = (const float*)d_in[4];  // (96, DI)
  const float* wdt  = (const float*)d_in[5];  // (DI, 64)
  const float* bdt  = (const float*)d_in[6];  // (DI,)
  const float* alog = (const float*)d_in[7];  // (DI, NS)
  const float* dpar = (const float*)d_in[8];  // (DI,)
  const float* wout = (const float*)d_in[9];  // (DM, DI)
  float* out = (float*)d_out;                 // (B,L,DM) f32

  char* ws = (char*)d_ws;
  size_t off = 0;
  auto alloc = [&](size_t bytes) -> void* {
    void* p = ws + off;
    off += (bytes + 255) & ~(size_t)255;
    return p;
  };
  u16*   hs_b   = (u16*)  alloc((size_t)BL * DM * 2);        // 8 MB
  u16*   win_b  = (u16*)  alloc((size_t)2 * DI * DM * 2);    // 8 MB
  u16*   wxp_b  = (u16*)  alloc((size_t)96 * DI * 2);        // 0.4 MB
  u16*   wout_b = (u16*)  alloc((size_t)DM * DI * 2);        // 4 MB
  float* xbuf   = (float*)alloc((size_t)BL * DI * 4);        // 32 MB
  float* zbuf   = (float*)alloc((size_t)BL * DI * 4);        // 32 MB
  float* ubuf   = (float*)alloc((size_t)BL * DI * 4);        // 32 MB
  u16*   ub16   = (u16*)  alloc((size_t)BL * DI * 2);        // 16 MB
  float* xdbl   = (float*)alloc((size_t)BL * 96 * 4);        // 1.5 MB
  float* Pbuf   = (float*)alloc((size_t)Bsz * NC * DI * NS * 4);  // 8.4 MB
  float* Sbuf   = (float*)alloc((size_t)Bsz * NC * DI * NS * 4);  // 8.4 MB
  float* deltab = xbuf;   // reuse: x consumed by conv before dt_gemm writes delta
  u16*   y_b    = ub16;   // reuse: u_bf16 consumed by gemm_wave16 before scan writes y
  float* Hin    = Pbuf;   // alias: scan_combine does per-thread read-P-then-write-Hin

  const int thr = 256;
  cvt_f32_bf16<<<(BL * DM / 4 + thr - 1) / thr, thr, 0, stream>>>(hs, hs_b, BL * DM);
  cvt_f32_bf16<<<(2 * DI * DM / 4 + thr - 1) / thr, thr, 0, stream>>>(win, win_b, 2 * DI * DM);
  cvt_f32_bf16<<<(96 * DI / 4 + thr - 1) / thr, thr, 0, stream>>>(wxp, wxp_b, 96 * DI);
  cvt_f32_bf16<<<(DM * DI / 4 + thr - 1) / thr, thr, 0, stream>>>(wout, wout_b, DM * DI);

  // GEMM1: xz = hs @ in_proj_w^T   (M=4096, N=4096, K=1024), split cols into x | z
  {
    dim3 g(4096 / 128, BL / 128);
    gemm128_bt<<<g, 256, 0, stream>>>(hs_b, win_b, xbuf, zbuf, DI, DI, DI, DM);
  }

  // conv + SiLU -> u (f32 + bf16)
  conv_silu_kernel<<<(BL * DI) / 256, 256, 0, stream>>>(xbuf, cw, cb, ubuf, ub16);

  // GEMM2: x_dbl = u @ x_proj_w^T  (M=4096, N=96, K=2048)
  gemm_wave16_bt<<<(BL / 16) * (96 / 16) / 4, 256, 0, stream>>>(ub16, wxp_b, xdbl, BL, 96, DI);

  // GEMM3 (f32): delta = softplus(dt_lo @ dt_proj_w^T + b)
  {
    dim3 g(DI / 256, BL / 16);
    dt_gemm_kernel<<<g, 256, 0, stream>>>(xdbl, wdt, bdt, deltab);
  }

  // chunked selective scan (thread-owns-channel layout)
  {
    dim3 gA(DI / 256, NC, Bsz);
    scan_chunk_ps<<<gA, 256, 0, stream>>>(deltab, ubuf, xdbl, alog, Pbuf, Sbuf);
    scan_combine<<<(Bsz * DI * NS) / 256, 256, 0, stream>>>(Pbuf, Sbuf, Hin);
    scan_chunk_y<<<gA, 256, 0, stream>>>(deltab, ubuf, xdbl, alog, dpar, zbuf, Hin, y_b);
  }

  // GEMM4: out = y @ out_proj_w^T  (M=4096, N=1024, K=2048) -> d_out f32
  {
    dim3 g(DM / 128, BL / 128);
    gemm128_bt<<<g, 256, 0, stream>>>(y_b, wout_b, out, out, DM, DM, DM, DI);
  }
}

// Round 5
// 294.273 us; speedup vs baseline: 7.6710x; 1.0617x over previous
//
#include <hip/hip_runtime.h>
#include <cstdint>
#include <cstddef>

// ---- problem constants ----
#define Bsz  2
#define Lseq 2048
#define DM   1024
#define DI   2048
#define NS   16
#define RR   64
#define BL   (Bsz * Lseq)   // 4096 rows
#define TC   64             // scan chunk length
#define NC   (Lseq / TC)    // 32 chunks

typedef unsigned short u16;
typedef __attribute__((ext_vector_type(8))) short short8;   // 8 bf16 (4 VGPRs)
typedef __attribute__((ext_vector_type(4))) float f32x4;    // 4 f32 acc

__device__ __forceinline__ u16 f32_to_bf16(float f) {
  union { float f; unsigned int u; } v; v.f = f;
  unsigned int lsb = (v.u >> 16) & 1u;
  v.u += 0x7fffu + lsb;           // round-to-nearest-even
  return (u16)(v.u >> 16);
}
__device__ __forceinline__ float bf16_to_f32(u16 h) {
  union { unsigned int u; float f; } v; v.u = ((unsigned int)h) << 16;
  return v.f;
}

// ---------------- f32 -> bf16 conversion ----------------
__global__ void cvt_f32_bf16(const float* __restrict__ src, u16* __restrict__ dst, int n) {
  int i = (blockIdx.x * blockDim.x + threadIdx.x) * 4;
  if (i + 4 <= n) {
    float4 v = *(const float4*)(src + i);
    dst[i + 0] = f32_to_bf16(v.x);
    dst[i + 1] = f32_to_bf16(v.y);
    dst[i + 2] = f32_to_bf16(v.z);
    dst[i + 3] = f32_to_bf16(v.w);
  } else {
    for (; i < n; ++i) dst[i] = f32_to_bf16(src[i]);
  }
}

// ---------------- split f32 -> bf16 hi + bf16 lo (residual) ----------------
// contiguous source (dtw: DI x 64)
__global__ void split_bf16_kernel(const float* __restrict__ src,
                                  u16* __restrict__ hi, u16* __restrict__ lo, int n) {
  int i = blockIdx.x * blockDim.x + threadIdx.x;
  if (i >= n) return;
  const float v = src[i];
  const u16 h = f32_to_bf16(v);
  hi[i] = h;
  lo[i] = f32_to_bf16(v - bf16_to_f32(h));
}

// strided source: dt_lo = xdbl[:, 0:64] with row stride 96
__global__ void split_dt_kernel(const float* __restrict__ xdbl,
                                u16* __restrict__ hi, u16* __restrict__ lo) {
  int i = blockIdx.x * blockDim.x + threadIdx.x;   // over BL*64
  if (i >= BL * 64) return;
  const int m = i >> 6, k = i & 63;
  const float v = xdbl[(size_t)m * 96 + k];
  const u16 h = f32_to_bf16(v);
  hi[i] = h;
  lo[i] = f32_to_bf16(v - bf16_to_f32(h));
}

// ---------------- 128x128-tile bf16 MFMA GEMM (m97 structure) ----------------
__device__ __forceinline__ void gload_lds16(const u16* g, u16* l) {
  __builtin_amdgcn_global_load_lds(
      (const __attribute__((address_space(1))) unsigned int*)g,
      (__attribute__((address_space(3))) unsigned int*)l,
      16, 0, 0);
}

__global__ __launch_bounds__(256) void gemm128_bt(
    const u16* __restrict__ A, const u16* __restrict__ Bt,
    float* __restrict__ outA, float* __restrict__ outB,
    int split, int ldA, int ldB, int K)
{
  __shared__ __align__(16) u16 As[128 * 32];
  __shared__ __align__(16) u16 Bs[128 * 32];
  const int tid  = threadIdx.x;
  const int lane = tid & 63;
  const int wid  = tid >> 6;
  const int m0 = blockIdx.y * 128;
  const int n0 = blockIdx.x * 128;
  const int wr = wid >> 1, wc = wid & 1;

  const f32x4 zero = {0.f, 0.f, 0.f, 0.f};
  f32x4 acc[4][4];
#pragma unroll
  for (int i = 0; i < 4; ++i)
#pragma unroll
    for (int j = 0; j < 4; ++j) acc[i][j] = zero;

  const int l16 = lane * 16;

  for (int k0 = 0; k0 < K; k0 += 32) {
    __syncthreads();
#pragma unroll
    for (int c = 0; c < 2; ++c) {
      const int base = c * 4096 + wid * 1024;
      const int ofs  = base + l16;
      const int row  = ofs >> 6;
      const int col  = (ofs >> 1) & 31;
      gload_lds16(A  + (size_t)(m0 + row) * K + k0 + col, (u16*)((char*)As + base));
      gload_lds16(Bt + (size_t)(n0 + row) * K + k0 + col, (u16*)((char*)Bs + base));
    }
    __syncthreads();

    const int kk = (lane >> 4) * 8;
    const int ra = wr * 64 + (lane & 15);
    const int rb = wc * 64 + (lane & 15);
    short8 af[4], bf[4];
#pragma unroll
    for (int i = 0; i < 4; ++i) af[i] = *(const short8*)&As[(ra + i * 16) * 32 + kk];
#pragma unroll
    for (int j = 0; j < 4; ++j) bf[j] = *(const short8*)&Bs[(rb + j * 16) * 32 + kk];
#pragma unroll
    for (int i = 0; i < 4; ++i)
#pragma unroll
      for (int j = 0; j < 4; ++j)
        acc[i][j] = __builtin_amdgcn_mfma_f32_16x16x32_bf16(af[i], bf[j], acc[i][j], 0, 0, 0);
  }

  const int cr = (lane >> 4) * 4;
  const int cc = lane & 15;
#pragma unroll
  for (int i = 0; i < 4; ++i)
#pragma unroll
    for (int j = 0; j < 4; ++j)
#pragma unroll
      for (int r = 0; r < 4; ++r) {
        const int m = m0 + wr * 64 + i * 16 + cr + r;
        const int n = n0 + wc * 64 + j * 16 + cc;
        const float v = acc[i][j][r];
        if (n < split) outA[(size_t)m * ldA + n] = v;
        else           outB[(size_t)m * ldB + (n - split)] = v;
      }
}

// ---------------- small-N GEMM: one wave per 16x16 tile (x_proj) ----------------
__global__ __launch_bounds__(256) void gemm_wave16_bt(
    const u16* __restrict__ A, const u16* __restrict__ Bt,
    float* __restrict__ C, int M, int N, int K)
{
  const int wg   = blockIdx.x * 4 + (threadIdx.x >> 6);
  const int lane = threadIdx.x & 63;
  const int ntiles = N / 16;
  const int mt = wg / ntiles, nt = wg % ntiles;
  if (mt * 16 >= M) return;

  const u16* arow = A  + (size_t)(mt * 16 + (lane & 15)) * K + ((lane >> 4) * 8);
  const u16* brow = Bt + (size_t)(nt * 16 + (lane & 15)) * K + ((lane >> 4) * 8);
  f32x4 acc = {0.f, 0.f, 0.f, 0.f};
  for (int k0 = 0; k0 < K; k0 += 32) {
    short8 a = *(const short8*)(arow + k0);
    short8 b = *(const short8*)(brow + k0);
    acc = __builtin_amdgcn_mfma_f32_16x16x32_bf16(a, b, acc, 0, 0, 0);
  }
  const int cr = (lane >> 4) * 4, cc = lane & 15;
#pragma unroll
  for (int r = 0; r < 4; ++r)
    C[(size_t)(mt * 16 + cr + r) * N + nt * 16 + cc] = acc[r];
}

// ---------------- dt GEMM via split-bf16 MFMA + fused softplus ----------------
// s = a_hi*b_hi + a_hi*b_lo + a_lo*b_hi  (error ~1e-5, f32-equivalent here)
// M=4096 (BL), N=2048 (DI), K=64. One wave per 16x16 tile, direct-from-global
// (A/B splits are L2-resident: 1 MB + 0.5 MB). Replaces the f32 VALU kernel
// that was issue-bound at 65 us (log1pf expansion + 1 ds_read per 4 FMA).
__global__ __launch_bounds__(256) void dt_gemm_mfma(
    const u16* __restrict__ ahi, const u16* __restrict__ alo,
    const u16* __restrict__ bhi, const u16* __restrict__ blo,
    const float* __restrict__ dtb, float* __restrict__ delta)
{
  const int wg   = blockIdx.x * 4 + (threadIdx.x >> 6);  // 256*128 tiles
  const int lane = threadIdx.x & 63;
  const int mt = wg >> 7, nt = wg & 127;

  const size_t aofs = (size_t)(mt * 16 + (lane & 15)) * 64 + ((lane >> 4) * 8);
  const size_t bofs = (size_t)(nt * 16 + (lane & 15)) * 64 + ((lane >> 4) * 8);

  f32x4 acc = {0.f, 0.f, 0.f, 0.f};
#pragma unroll
  for (int k0 = 0; k0 < 64; k0 += 32) {
    const short8 Ah = *(const short8*)(ahi + aofs + k0);
    const short8 Al = *(const short8*)(alo + aofs + k0);
    const short8 Bh = *(const short8*)(bhi + bofs + k0);
    const short8 Bl = *(const short8*)(blo + bofs + k0);
    acc = __builtin_amdgcn_mfma_f32_16x16x32_bf16(Ah, Bh, acc, 0, 0, 0);
    acc = __builtin_amdgcn_mfma_f32_16x16x32_bf16(Ah, Bl, acc, 0, 0, 0);
    acc = __builtin_amdgcn_mfma_f32_16x16x32_bf16(Al, Bh, acc, 0, 0, 0);
  }

  const int cr = (lane >> 4) * 4, cc = lane & 15;
  const int n  = nt * 16 + cc;
  const float b = dtb[n];
#pragma unroll
  for (int r = 0; r < 4; ++r) {
    const float s = acc[r] + b;
    // branch-free softplus: max(s,0) + log(1 + exp(-|s|)); abs err ~2^-24
    const float sp = fmaxf(s, 0.f) + __logf(1.f + __expf(-fabsf(s)));
    delta[(size_t)(mt * 16 + cr + r) * DI + n] = sp;
  }
}

// ---------------- causal depthwise conv (W=4) + bias + SiLU ----------------
__global__ void conv_silu_kernel(const float* __restrict__ x,
                                 const float* __restrict__ cw, const float* __restrict__ cb,
                                 float* __restrict__ uf, u16* __restrict__ ub)
{
  const int idx = blockIdx.x * blockDim.x + threadIdx.x;   // over BL*DI
  if (idx >= BL * DI) return;
  const int d  = idx & (DI - 1);
  const int bl = idx >> 11;            // DI = 2048
  const int l  = bl & (Lseq - 1);      // Lseq = 2048
  const float4 w = *(const float4*)(cw + d * 4);
  float acc = cb[d];
  const float* xp = x + (size_t)bl * DI + d;
  const float x0 = (l >= 3) ? xp[-3 * DI] : 0.f;
  const float x1 = (l >= 2) ? xp[-2 * DI] : 0.f;
  const float x2 = (l >= 1) ? xp[-1 * DI] : 0.f;
  const float x3 = xp[0];
  acc += x0 * w.x + x1 * w.y + x2 * w.z + x3 * w.w;
  const float s = acc / (1.f + __expf(-acc));   // SiLU
  uf[idx] = s;
  ub[idx] = f32_to_bf16(s);
}

// ================= chunked selective scan =================
// Thread-owns-channel layout: each thread owns one d, holds all NS=16 states
// in VGPRs; n-reduction = 16 in-register FMAs, zero cross-lane ops.
// P/S/Hin layout: [(b*NC+c)*NS + n]*DI + d  (coalesced over d).

// ---- Kernel A: chunk-local products/partials ----
__global__ __launch_bounds__(256) void scan_chunk_ps(
    const float* __restrict__ delta, const float* __restrict__ u,
    const float* __restrict__ xdbl, const float* __restrict__ alog,
    float* __restrict__ Pout, float* __restrict__ Sout)
{
  __shared__ float Bl[TC][NS];
  const int b   = blockIdx.z;
  const int c   = blockIdx.y;
  const int d   = blockIdx.x * 256 + threadIdx.x;
  const int tid = threadIdx.x;
  const size_t rowBase = (size_t)b * Lseq + (size_t)c * TC;

  {
    const int row = tid >> 2, c4 = (tid & 3) * 4;
    *(float4*)&Bl[row][c4] = *(const float4*)&xdbl[(rowBase + row) * 96 + RR + c4];
  }
  __syncthreads();

  float A[NS];
#pragma unroll
  for (int n4 = 0; n4 < 4; ++n4) {
    const float4 a4 = *(const float4*)&alog[(size_t)d * NS + n4 * 4];
    A[n4 * 4 + 0] = -__expf(a4.x);
    A[n4 * 4 + 1] = -__expf(a4.y);
    A[n4 * 4 + 2] = -__expf(a4.z);
    A[n4 * 4 + 3] = -__expf(a4.w);
  }

  float h[NS], P[NS];
#pragma unroll
  for (int n = 0; n < NS; ++n) { h[n] = 0.f; P[n] = 1.f; }

#pragma unroll 4
  for (int t = 0; t < TC; ++t) {
    const float dt  = delta[(rowBase + t) * DI + d];
    const float ut  = u[(rowBase + t) * DI + d];
    const float dtu = dt * ut;
#pragma unroll
    for (int n = 0; n < NS; ++n) {
      const float dA = __expf(dt * A[n]);
      P[n] *= dA;
      h[n] = dA * h[n] + dtu * Bl[t][n];
    }
  }

  const size_t base = (size_t)(b * NC + c) * NS * DI + d;
#pragma unroll
  for (int n = 0; n < NS; ++n) {
    Pout[base + (size_t)n * DI] = P[n];
    Sout[base + (size_t)n * DI] = h[n];
  }
}

// ---- Kernel B: inter-chunk combine (serial over NC only) ----
__global__ __launch_bounds__(256) void scan_combine(
    const float* __restrict__ P, const float* __restrict__ S,
    float* __restrict__ Hin)   // may alias P (per-thread read-before-write)
{
  const int gid = blockIdx.x * 256 + threadIdx.x;  // over Bsz*NS*DI = 65536
  const int b   = gid >> 15;                       // NS*DI = 32768
  const int nd  = gid & 32767;
  float h = 0.f;
  for (int c = 0; c < NC; ++c) {
    const size_t o = (size_t)(b * NC + c) * (NS * DI) + nd;
    const float Pc = P[o];
    const float Sc = S[o];
    Hin[o] = h;
    h = Pc * h + Sc;
  }
}

// ---- Kernel C: chunk-local y with seeded state, + skip + gate -> bf16 ----
__global__ __launch_bounds__(256) void scan_chunk_y(
    const float* __restrict__ delta, const float* __restrict__ u,
    const float* __restrict__ xdbl, const float* __restrict__ alog,
    const float* __restrict__ dpar, const float* __restrict__ z,
    const float* __restrict__ Hin, u16* __restrict__ yb)
{
  __shared__ float Bl[TC][NS];
  __shared__ float Cl[TC][NS];
  const int b   = blockIdx.z;
  const int c   = blockIdx.y;
  const int d   = blockIdx.x * 256 + threadIdx.x;
  const int tid = threadIdx.x;
  const size_t rowBase = (size_t)b * Lseq + (size_t)c * TC;

  {
    const int row = tid >> 2, c4 = (tid & 3) * 4;
    *(float4*)&Bl[row][c4] = *(const float4*)&xdbl[(rowBase + row) * 96 + RR + c4];
    *(float4*)&Cl[row][c4] = *(const float4*)&xdbl[(rowBase + row) * 96 + RR + NS + c4];
  }
  __syncthreads();

  float A[NS];
#pragma unroll
  for (int n4 = 0; n4 < 4; ++n4) {
    const float4 a4 = *(const float4*)&alog[(size_t)d * NS + n4 * 4];
    A[n4 * 4 + 0] = -__expf(a4.x);
    A[n4 * 4 + 1] = -__expf(a4.y);
    A[n4 * 4 + 2] = -__expf(a4.z);
    A[n4 * 4 + 3] = -__expf(a4.w);
  }
  const float Dv = dpar[d];

  float h[NS];
  const size_t sbase = (size_t)(b * NC + c) * NS * DI + d;
#pragma unroll
  for (int n = 0; n < NS; ++n) h[n] = Hin[sbase + (size_t)n * DI];

#pragma unroll 4
  for (int t = 0; t < TC; ++t) {
    const float dt  = delta[(rowBase + t) * DI + d];
    const float ut  = u[(rowBase + t) * DI + d];
    const float zv  = z[(rowBase + t) * DI + d];
    const float dtu = dt * ut;
    float y = 0.f;
#pragma unroll
    for (int n = 0; n < NS; ++n) {
      const float dA = __expf(dt * A[n]);
      h[n] = dA * h[n] + dtu * Bl[t][n];
      y += h[n] * Cl[t][n];
    }
    const float yv = y + ut * Dv;
    const float g  = zv / (1.f + __expf(-zv));   // z * sigmoid(z)
    yb[(rowBase + t) * DI + d] = f32_to_bf16(yv * g);
  }
}

// ---------------- host launcher ----------------
extern "C" void kernel_launch(void* const* d_in, const int* in_sizes, int n_in,
                              void* d_out, int out_size, void* d_ws, size_t ws_size,
                              hipStream_t stream)
{
  const float* hs   = (const float*)d_in[0];  // (B,L,DM)
  const float* win  = (const float*)d_in[1];  // (2*DI, DM)
  const float* cw   = (const float*)d_in[2];  // (DI, 4)
  const float* cb   = (const float*)d_in[3];  // (DI,)
  const float* wxp  = (const float*)d_in[4];  // (96, DI)
  const float* wdt  = (const float*)d_in[5];  // (DI, 64)
  const float* bdt  = (const float*)d_in[6];  // (DI,)
  const float* alog = (const float*)d_in[7];  // (DI, NS)
  const float* dpar = (const float*)d_in[8];  // (DI,)
  const float* wout = (const float*)d_in[9];  // (DM, DI)
  float* out = (float*)d_out;                 // (B,L,DM) f32

  char* ws = (char*)d_ws;
  size_t off = 0;
  auto alloc = [&](size_t bytes) -> void* {
    void* p = ws + off;
    off += (bytes + 255) & ~(size_t)255;
    return p;
  };
  u16*   hs_b   = (u16*)  alloc((size_t)BL * DM * 2);        // 8 MB
  u16*   win_b  = (u16*)  alloc((size_t)2 * DI * DM * 2);    // 8 MB
  u16*   wxp_b  = (u16*)  alloc((size_t)96 * DI * 2);        // 0.4 MB
  u16*   wout_b = (u16*)  alloc((size_t)DM * DI * 2);        // 4 MB
  float* xbuf   = (float*)alloc((size_t)BL * DI * 4);        // 32 MB
  float* zbuf   = (float*)alloc((size_t)BL * DI * 4);        // 32 MB
  float* ubuf   = (float*)alloc((size_t)BL * DI * 4);        // 32 MB
  u16*   ub16   = (u16*)  alloc((size_t)BL * DI * 2);        // 16 MB
  float* xdbl   = (float*)alloc((size_t)BL * 96 * 4);        // 1.5 MB
  float* Pbuf   = (float*)alloc((size_t)Bsz * NC * DI * NS * 4);  // 8.4 MB
  float* Sbuf   = (float*)alloc((size_t)Bsz * NC * DI * NS * 4);  // 8.4 MB
  u16*   dt_hi  = (u16*)  alloc((size_t)BL * 64 * 2);        // 0.5 MB
  u16*   dt_lo  = (u16*)  alloc((size_t)BL * 64 * 2);        // 0.5 MB
  u16*   w_hi   = (u16*)  alloc((size_t)DI * 64 * 2);        // 0.25 MB
  u16*   w_lo   = (u16*)  alloc((size_t)DI * 64 * 2);        // 0.25 MB
  float* deltab = xbuf;   // reuse: x consumed by conv before dt_gemm writes delta
  u16*   y_b    = ub16;   // reuse: u_bf16 consumed by gemm_wave16 before scan writes y
  float* Hin    = Pbuf;   // alias: scan_combine does per-thread read-P-then-write-Hin

  const int thr = 256;
  cvt_f32_bf16<<<(BL * DM / 4 + thr - 1) / thr, thr, 0, stream>>>(hs, hs_b, BL * DM);
  cvt_f32_bf16<<<(2 * DI * DM / 4 + thr - 1) / thr, thr, 0, stream>>>(win, win_b, 2 * DI * DM);
  cvt_f32_bf16<<<(96 * DI / 4 + thr - 1) / thr, thr, 0, stream>>>(wxp, wxp_b, 96 * DI);
  cvt_f32_bf16<<<(DM * DI / 4 + thr - 1) / thr, thr, 0, stream>>>(wout, wout_b, DM * DI);
  split_bf16_kernel<<<(DI * 64) / thr, thr, 0, stream>>>(wdt, w_hi, w_lo, DI * 64);

  // GEMM1: xz = hs @ in_proj_w^T   (M=4096, N=4096, K=1024), split cols into x | z
  {
    dim3 g(4096 / 128, BL / 128);
    gemm128_bt<<<g, 256, 0, stream>>>(hs_b, win_b, xbuf, zbuf, DI, DI, DI, DM);
  }

  // conv + SiLU -> u (f32 + bf16)
  conv_silu_kernel<<<(BL * DI) / 256, 256, 0, stream>>>(xbuf, cw, cb, ubuf, ub16);

  // GEMM2: x_dbl = u @ x_proj_w^T  (M=4096, N=96, K=2048)
  gemm_wave16_bt<<<(BL / 16) * (96 / 16) / 4, 256, 0, stream>>>(ub16, wxp_b, xdbl, BL, 96, DI);

  // GEMM3: delta = softplus(dt_lo @ dt_proj_w^T + b) via split-bf16 MFMA
  split_dt_kernel<<<(BL * 64) / thr, thr, 0, stream>>>(xdbl, dt_hi, dt_lo);
  dt_gemm_mfma<<<(256 * 128) / 4, 256, 0, stream>>>(dt_hi, dt_lo, w_hi, w_lo, bdt, deltab);

  // chunked selective scan (thread-owns-channel layout)
  {
    dim3 gA(DI / 256, NC, Bsz);
    scan_chunk_ps<<<gA, 256, 0, stream>>>(deltab, ubuf, xdbl, alog, Pbuf, Sbuf);
    scan_combine<<<(Bsz * DI * NS) / 256, 256, 0, stream>>>(Pbuf, Sbuf, Hin);
    scan_chunk_y<<<gA, 256, 0, stream>>>(deltab, ubuf, xdbl, alog, dpar, zbuf, Hin, y_b);
  }

  // GEMM4: out = y @ out_proj_w^T  (M=4096, N=1024, K=2048) -> d_out f32
  {
    dim3 g(DM / 128, BL / 128);
    gemm128_bt<<<g, 256, 0, stream>>>(y_b, wout_b, out, out, DM, DM, DM, DI);
  }
}

// Round 6
// 294.088 us; speedup vs baseline: 7.6758x; 1.0006x over previous
//
#include <hip/hip_runtime.h>
#include <cstdint>
#include <cstddef>

// ---- problem constants ----
#define Bsz  2
#define Lseq 2048
#define DM   1024
#define DI   2048
#define NS   16
#define RR   64
#define BL   (Bsz * Lseq)   // 4096 rows
#define TC   64             // scan chunk length
#define NC   (Lseq / TC)    // 32 chunks

typedef unsigned short u16;
typedef __attribute__((ext_vector_type(4))) unsigned short u16x4;
typedef __attribute__((ext_vector_type(8))) short short8;   // 8 bf16 (4 VGPRs)
typedef __attribute__((ext_vector_type(4))) float f32x4;    // 4 f32 acc

__device__ __forceinline__ u16 f32_to_bf16(float f) {
  union { float f; unsigned int u; } v; v.f = f;
  unsigned int lsb = (v.u >> 16) & 1u;
  v.u += 0x7fffu + lsb;           // round-to-nearest-even
  return (u16)(v.u >> 16);
}
__device__ __forceinline__ float bf16_to_f32(u16 h) {
  union { unsigned int u; float f; } v; v.u = ((unsigned int)h) << 16;
  return v.f;
}

// ---------------- f32 -> bf16 conversion ----------------
__global__ void cvt_f32_bf16(const float* __restrict__ src, u16* __restrict__ dst, int n) {
  int i = (blockIdx.x * blockDim.x + threadIdx.x) * 4;
  if (i + 4 <= n) {
    float4 v = *(const float4*)(src + i);
    dst[i + 0] = f32_to_bf16(v.x);
    dst[i + 1] = f32_to_bf16(v.y);
    dst[i + 2] = f32_to_bf16(v.z);
    dst[i + 3] = f32_to_bf16(v.w);
  } else {
    for (; i < n; ++i) dst[i] = f32_to_bf16(src[i]);
  }
}

// ---------------- split f32 -> bf16 hi + bf16 lo (dtw weights) ----------------
__global__ void split_bf16_kernel(const float* __restrict__ src,
                                  u16* __restrict__ hi, u16* __restrict__ lo, int n) {
  int i = blockIdx.x * blockDim.x + threadIdx.x;
  if (i >= n) return;
  const float v = src[i];
  const u16 h = f32_to_bf16(v);
  hi[i] = h;
  lo[i] = f32_to_bf16(v - bf16_to_f32(h));
}

// ---------------- 128x128-tile bf16 MFMA GEMM (m97 structure) ----------------
__device__ __forceinline__ void gload_lds16(const u16* g, u16* l) {
  __builtin_amdgcn_global_load_lds(
      (const __attribute__((address_space(1))) unsigned int*)g,
      (__attribute__((address_space(3))) unsigned int*)l,
      16, 0, 0);
}

// BF16OUT=true: outputs stored as bf16 (x,z intermediates); false: f32 (final out)
template<bool BF16OUT>
__global__ __launch_bounds__(256) void gemm128_bt(
    const u16* __restrict__ A, const u16* __restrict__ Bt,
    void* __restrict__ outA_, void* __restrict__ outB_,
    int split, int ldA, int ldB, int K)
{
  __shared__ __align__(16) u16 As[128 * 32];
  __shared__ __align__(16) u16 Bs[128 * 32];
  const int tid  = threadIdx.x;
  const int lane = tid & 63;
  const int wid  = tid >> 6;
  const int m0 = blockIdx.y * 128;
  const int n0 = blockIdx.x * 128;
  const int wr = wid >> 1, wc = wid & 1;

  const f32x4 zero = {0.f, 0.f, 0.f, 0.f};
  f32x4 acc[4][4];
#pragma unroll
  for (int i = 0; i < 4; ++i)
#pragma unroll
    for (int j = 0; j < 4; ++j) acc[i][j] = zero;

  const int l16 = lane * 16;

  for (int k0 = 0; k0 < K; k0 += 32) {
    __syncthreads();
#pragma unroll
    for (int c = 0; c < 2; ++c) {
      const int base = c * 4096 + wid * 1024;
      const int ofs  = base + l16;
      const int row  = ofs >> 6;
      const int col  = (ofs >> 1) & 31;
      gload_lds16(A  + (size_t)(m0 + row) * K + k0 + col, (u16*)((char*)As + base));
      gload_lds16(Bt + (size_t)(n0 + row) * K + k0 + col, (u16*)((char*)Bs + base));
    }
    __syncthreads();

    const int kk = (lane >> 4) * 8;
    const int ra = wr * 64 + (lane & 15);
    const int rb = wc * 64 + (lane & 15);
    short8 af[4], bf[4];
#pragma unroll
    for (int i = 0; i < 4; ++i) af[i] = *(const short8*)&As[(ra + i * 16) * 32 + kk];
#pragma unroll
    for (int j = 0; j < 4; ++j) bf[j] = *(const short8*)&Bs[(rb + j * 16) * 32 + kk];
#pragma unroll
    for (int i = 0; i < 4; ++i)
#pragma unroll
      for (int j = 0; j < 4; ++j)
        acc[i][j] = __builtin_amdgcn_mfma_f32_16x16x32_bf16(af[i], bf[j], acc[i][j], 0, 0, 0);
  }

  const int cr = (lane >> 4) * 4;
  const int cc = lane & 15;
#pragma unroll
  for (int i = 0; i < 4; ++i)
#pragma unroll
    for (int j = 0; j < 4; ++j)
#pragma unroll
      for (int r = 0; r < 4; ++r) {
        const int m = m0 + wr * 64 + i * 16 + cr + r;
        const int n = n0 + wc * 64 + j * 16 + cc;
        const float v = acc[i][j][r];
        const bool isA = (n < split);
        const int  nn  = isA ? n : n - split;
        const int  ld  = isA ? ldA : ldB;
        if constexpr (BF16OUT) {
          u16* o = isA ? (u16*)outA_ : (u16*)outB_;
          o[(size_t)m * ld + nn] = f32_to_bf16(v);
        } else {
          float* o = isA ? (float*)outA_ : (float*)outB_;
          o[(size_t)m * ld + nn] = v;
        }
      }
}

// ---------------- x_proj GEMM (N=96) + fused dt hi/lo split ----------------
// One wave per 16x16 tile. Columns [0,64) -> dt_hi/dt_lo (split straight from
// the f32 accumulator, replacing the split_dt kernel); [64,96) -> xdbl B/C cols.
__global__ __launch_bounds__(256) void gemm_xproj(
    const u16* __restrict__ A, const u16* __restrict__ Bt,
    float* __restrict__ xdbl, u16* __restrict__ dhi, u16* __restrict__ dlo)
{
  const int wg   = blockIdx.x * 4 + (threadIdx.x >> 6);   // over 256*6 tiles
  const int lane = threadIdx.x & 63;
  const int mt = wg / 6, nt = wg % 6;

  const u16* arow = A  + (size_t)(mt * 16 + (lane & 15)) * DI + ((lane >> 4) * 8);
  const u16* brow = Bt + (size_t)(nt * 16 + (lane & 15)) * DI + ((lane >> 4) * 8);
  f32x4 acc = {0.f, 0.f, 0.f, 0.f};
  for (int k0 = 0; k0 < DI; k0 += 32) {
    short8 a = *(const short8*)(arow + k0);
    short8 b = *(const short8*)(brow + k0);
    acc = __builtin_amdgcn_mfma_f32_16x16x32_bf16(a, b, acc, 0, 0, 0);
  }
  const int cr = (lane >> 4) * 4, cc = lane & 15;
  const int n  = nt * 16 + cc;
#pragma unroll
  for (int r = 0; r < 4; ++r) {
    const int m = mt * 16 + cr + r;
    const float v = acc[r];
    if (n < RR) {
      const u16 h = f32_to_bf16(v);
      dhi[(size_t)m * RR + n] = h;
      dlo[(size_t)m * RR + n] = f32_to_bf16(v - bf16_to_f32(h));
    } else {
      xdbl[(size_t)m * 96 + n] = v;
    }
  }
}

// ---------------- dt GEMM via split-bf16 MFMA + fused softplus ----------------
// s = a_hi*b_hi + a_hi*b_lo + a_lo*b_hi  (error ~1e-5, f32-equivalent here)
__global__ __launch_bounds__(256) void dt_gemm_mfma(
    const u16* __restrict__ ahi, const u16* __restrict__ alo,
    const u16* __restrict__ bhi, const u16* __restrict__ blo,
    const float* __restrict__ dtb, float* __restrict__ delta)
{
  const int wg   = blockIdx.x * 4 + (threadIdx.x >> 6);  // 256*128 tiles
  const int lane = threadIdx.x & 63;
  const int mt = wg >> 7, nt = wg & 127;

  const size_t aofs = (size_t)(mt * 16 + (lane & 15)) * 64 + ((lane >> 4) * 8);
  const size_t bofs = (size_t)(nt * 16 + (lane & 15)) * 64 + ((lane >> 4) * 8);

  f32x4 acc = {0.f, 0.f, 0.f, 0.f};
#pragma unroll
  for (int k0 = 0; k0 < 64; k0 += 32) {
    const short8 Ah = *(const short8*)(ahi + aofs + k0);
    const short8 Al = *(const short8*)(alo + aofs + k0);
    const short8 Bh = *(const short8*)(bhi + bofs + k0);
    const short8 Bl = *(const short8*)(blo + bofs + k0);
    acc = __builtin_amdgcn_mfma_f32_16x16x32_bf16(Ah, Bh, acc, 0, 0, 0);
    acc = __builtin_amdgcn_mfma_f32_16x16x32_bf16(Ah, Bl, acc, 0, 0, 0);
    acc = __builtin_amdgcn_mfma_f32_16x16x32_bf16(Al, Bh, acc, 0, 0, 0);
  }

  const int cr = (lane >> 4) * 4, cc = lane & 15;
  const int n  = nt * 16 + cc;
  const float b = dtb[n];
#pragma unroll
  for (int r = 0; r < 4; ++r) {
    const float s = acc[r] + b;
    // branch-free softplus: max(s,0) + log(1 + exp(-|s|)); abs err ~2^-24
    const float sp = fmaxf(s, 0.f) + __logf(1.f + __expf(-fabsf(s)));
    delta[(size_t)(mt * 16 + cr + r) * DI + n] = sp;
  }
}

// ---------------- causal depthwise conv (W=4) + bias + SiLU, bf16 in/out ----
// 4 channels per thread (8B loads/stores per row — G13 vectorization).
__global__ void conv_silu_kernel(const u16* __restrict__ x,
                                 const float* __restrict__ cw, const float* __restrict__ cb,
                                 u16* __restrict__ ub)
{
  const int idx  = blockIdx.x * blockDim.x + threadIdx.x;   // over BL*DI/4
  const int base = idx * 4;
  const int d  = base & (DI - 1);
  const int bl = base >> 11;           // DI = 2048
  const int l  = bl & (Lseq - 1);      // Lseq = 2048
  const u16* xp = x + (size_t)bl * DI + d;
  const u16x4 zv = {0, 0, 0, 0};
  const u16x4 x3 = *(const u16x4*)xp;
  const u16x4 x2 = (l >= 1) ? *(const u16x4*)(xp - DI)     : zv;
  const u16x4 x1 = (l >= 2) ? *(const u16x4*)(xp - 2 * DI) : zv;
  const u16x4 x0 = (l >= 3) ? *(const u16x4*)(xp - 3 * DI) : zv;
  const float4 bias = *(const float4*)&cb[d];
  u16x4 out;
#pragma unroll
  for (int j = 0; j < 4; ++j) {
    const float4 w = *(const float4*)&cw[(d + j) * 4];
    float acc = ((const float*)&bias)[j];
    acc += bf16_to_f32(x0[j]) * w.x + bf16_to_f32(x1[j]) * w.y +
           bf16_to_f32(x2[j]) * w.z + bf16_to_f32(x3[j]) * w.w;
    const float s = acc / (1.f + __expf(-acc));   // SiLU
    out[j] = f32_to_bf16(s);
  }
  *(u16x4*)(ub + (size_t)bl * DI + d) = out;
}

// ================= chunked selective scan =================
// Thread-owns-channel layout: each thread owns one d, holds all NS=16 states
// in VGPRs; n-reduction = 16 in-register FMAs, zero cross-lane ops.
// P/S/Hin layout: [(b*NC+c)*NS + n]*DI + d  (coalesced over d).
// delta stays f32 (exp-sensitive); u,z are bf16.

// ---- Kernel A: chunk-local products/partials ----
__global__ __launch_bounds__(256) void scan_chunk_ps(
    const float* __restrict__ delta, const u16* __restrict__ u,
    const float* __restrict__ xdbl, const float* __restrict__ alog,
    float* __restrict__ Pout, float* __restrict__ Sout)
{
  __shared__ float Bl[TC][NS];
  const int b   = blockIdx.z;
  const int c   = blockIdx.y;
  const int d   = blockIdx.x * 256 + threadIdx.x;
  const int tid = threadIdx.x;
  const size_t rowBase = (size_t)b * Lseq + (size_t)c * TC;

  {
    const int row = tid >> 2, c4 = (tid & 3) * 4;
    *(float4*)&Bl[row][c4] = *(const float4*)&xdbl[(rowBase + row) * 96 + RR + c4];
  }
  __syncthreads();

  float A[NS];
#pragma unroll
  for (int n4 = 0; n4 < 4; ++n4) {
    const float4 a4 = *(const float4*)&alog[(size_t)d * NS + n4 * 4];
    A[n4 * 4 + 0] = -__expf(a4.x);
    A[n4 * 4 + 1] = -__expf(a4.y);
    A[n4 * 4 + 2] = -__expf(a4.z);
    A[n4 * 4 + 3] = -__expf(a4.w);
  }

  float h[NS], P[NS];
#pragma unroll
  for (int n = 0; n < NS; ++n) { h[n] = 0.f; P[n] = 1.f; }

#pragma unroll 4
  for (int t = 0; t < TC; ++t) {
    const float dt  = delta[(rowBase + t) * DI + d];
    const float ut  = bf16_to_f32(u[(rowBase + t) * DI + d]);
    const float dtu = dt * ut;
#pragma unroll
    for (int n = 0; n < NS; ++n) {
      const float dA = __expf(dt * A[n]);
      P[n] *= dA;
      h[n] = dA * h[n] + dtu * Bl[t][n];
    }
  }

  const size_t base = (size_t)(b * NC + c) * NS * DI + d;
#pragma unroll
  for (int n = 0; n < NS; ++n) {
    Pout[base + (size_t)n * DI] = P[n];
    Sout[base + (size_t)n * DI] = h[n];
  }
}

// ---- Kernel B: inter-chunk combine (serial over NC only) ----
__global__ __launch_bounds__(256) void scan_combine(
    const float* __restrict__ P, const float* __restrict__ S,
    float* __restrict__ Hin)   // may alias P (per-thread read-before-write)
{
  const int gid = blockIdx.x * 256 + threadIdx.x;  // over Bsz*NS*DI = 65536
  const int b   = gid >> 15;                       // NS*DI = 32768
  const int nd  = gid & 32767;
  float h = 0.f;
  for (int c = 0; c < NC; ++c) {
    const size_t o = (size_t)(b * NC + c) * (NS * DI) + nd;
    const float Pc = P[o];
    const float Sc = S[o];
    Hin[o] = h;
    h = Pc * h + Sc;
  }
}

// ---- Kernel C: chunk-local y with seeded state, + skip + gate -> bf16 ----
// yb may alias u (per-thread read-ut-then-write-y at the same index).
__global__ __launch_bounds__(256) void scan_chunk_y(
    const float* __restrict__ delta, const u16* __restrict__ u,
    const float* __restrict__ xdbl, const float* __restrict__ alog,
    const float* __restrict__ dpar, const u16* __restrict__ z,
    const float* __restrict__ Hin, u16* __restrict__ yb)
{
  __shared__ float Bl[TC][NS];
  __shared__ float Cl[TC][NS];
  const int b   = blockIdx.z;
  const int c   = blockIdx.y;
  const int d   = blockIdx.x * 256 + threadIdx.x;
  const int tid = threadIdx.x;
  const size_t rowBase = (size_t)b * Lseq + (size_t)c * TC;

  {
    const int row = tid >> 2, c4 = (tid & 3) * 4;
    *(float4*)&Bl[row][c4] = *(const float4*)&xdbl[(rowBase + row) * 96 + RR + c4];
    *(float4*)&Cl[row][c4] = *(const float4*)&xdbl[(rowBase + row) * 96 + RR + NS + c4];
  }
  __syncthreads();

  float A[NS];
#pragma unroll
  for (int n4 = 0; n4 < 4; ++n4) {
    const float4 a4 = *(const float4*)&alog[(size_t)d * NS + n4 * 4];
    A[n4 * 4 + 0] = -__expf(a4.x);
    A[n4 * 4 + 1] = -__expf(a4.y);
    A[n4 * 4 + 2] = -__expf(a4.z);
    A[n4 * 4 + 3] = -__expf(a4.w);
  }
  const float Dv = dpar[d];

  float h[NS];
  const size_t sbase = (size_t)(b * NC + c) * NS * DI + d;
#pragma unroll
  for (int n = 0; n < NS; ++n) h[n] = Hin[sbase + (size_t)n * DI];

#pragma unroll 4
  for (int t = 0; t < TC; ++t) {
    const float dt  = delta[(rowBase + t) * DI + d];
    const float ut  = bf16_to_f32(u[(rowBase + t) * DI + d]);
    const float zv  = bf16_to_f32(z[(rowBase + t) * DI + d]);
    const float dtu = dt * ut;
    float y = 0.f;
#pragma unroll
    for (int n = 0; n < NS; ++n) {
      const float dA = __expf(dt * A[n]);
      h[n] = dA * h[n] + dtu * Bl[t][n];
      y += h[n] * Cl[t][n];
    }
    const float yv = y + ut * Dv;
    const float g  = zv / (1.f + __expf(-zv));   // z * sigmoid(z)
    yb[(rowBase + t) * DI + d] = f32_to_bf16(yv * g);
  }
}

// ---------------- host launcher ----------------
extern "C" void kernel_launch(void* const* d_in, const int* in_sizes, int n_in,
                              void* d_out, int out_size, void* d_ws, size_t ws_size,
                              hipStream_t stream)
{
  const float* hs   = (const float*)d_in[0];  // (B,L,DM)
  const float* win  = (const float*)d_in[1];  // (2*DI, DM)
  const float* cw   = (const float*)d_in[2];  // (DI, 4)
  const float* cb   = (const float*)d_in[3];  // (DI,)
  const float* wxp  = (const float*)d_in[4];  // (96, DI)
  const float* wdt  = (const float*)d_in[5];  // (DI, 64)
  const float* bdt  = (const float*)d_in[6];  // (DI,)
  const float* alog = (const float*)d_in[7];  // (DI, NS)
  const float* dpar = (const float*)d_in[8];  // (DI,)
  const float* wout = (const float*)d_in[9];  // (DM, DI)
  float* out = (float*)d_out;                 // (B,L,DM) f32

  char* ws = (char*)d_ws;
  size_t off = 0;
  auto alloc = [&](size_t bytes) -> void* {
    void* p = ws + off;
    off += (bytes + 255) & ~(size_t)255;
    return p;
  };
  u16*   hs_b   = (u16*)  alloc((size_t)BL * DM * 2);        // 8 MB
  u16*   win_b  = (u16*)  alloc((size_t)2 * DI * DM * 2);    // 8 MB
  u16*   wxp_b  = (u16*)  alloc((size_t)96 * DI * 2);        // 0.4 MB
  u16*   wout_b = (u16*)  alloc((size_t)DM * DI * 2);        // 4 MB
  u16*   xbuf   = (u16*)  alloc((size_t)BL * DI * 2);        // 16 MB (bf16 x)
  u16*   zbuf   = (u16*)  alloc((size_t)BL * DI * 2);        // 16 MB (bf16 z)
  u16*   ub16   = (u16*)  alloc((size_t)BL * DI * 2);        // 16 MB (bf16 u)
  float* deltab = (float*)alloc((size_t)BL * DI * 4);        // 32 MB (f32 delta)
  float* xdbl   = (float*)alloc((size_t)BL * 96 * 4);        // 1.5 MB
  float* Pbuf   = (float*)alloc((size_t)Bsz * NC * DI * NS * 4);  // 8.4 MB
  float* Sbuf   = (float*)alloc((size_t)Bsz * NC * DI * NS * 4);  // 8.4 MB
  u16*   dt_hi  = (u16*)  alloc((size_t)BL * 64 * 2);        // 0.5 MB
  u16*   dt_lo  = (u16*)  alloc((size_t)BL * 64 * 2);        // 0.5 MB
  u16*   w_hi   = (u16*)  alloc((size_t)DI * 64 * 2);        // 0.25 MB
  u16*   w_lo   = (u16*)  alloc((size_t)DI * 64 * 2);        // 0.25 MB
  u16*   y_b    = ub16;   // alias: scan_y reads u[t] then writes y[t], same thread/index
  float* Hin    = Pbuf;   // alias: scan_combine does per-thread read-P-then-write-Hin

  const int thr = 256;
  cvt_f32_bf16<<<(BL * DM / 4 + thr - 1) / thr, thr, 0, stream>>>(hs, hs_b, BL * DM);
  cvt_f32_bf16<<<(2 * DI * DM / 4 + thr - 1) / thr, thr, 0, stream>>>(win, win_b, 2 * DI * DM);
  cvt_f32_bf16<<<(96 * DI / 4 + thr - 1) / thr, thr, 0, stream>>>(wxp, wxp_b, 96 * DI);
  cvt_f32_bf16<<<(DM * DI / 4 + thr - 1) / thr, thr, 0, stream>>>(wout, wout_b, DM * DI);
  split_bf16_kernel<<<(DI * 64) / thr, thr, 0, stream>>>(wdt, w_hi, w_lo, DI * 64);

  // GEMM1: xz = hs @ in_proj_w^T  (M=4096, N=4096, K=1024) -> bf16 x | bf16 z
  {
    dim3 g(4096 / 128, BL / 128);
    gemm128_bt<true><<<g, 256, 0, stream>>>(hs_b, win_b, xbuf, zbuf, DI, DI, DI, DM);
  }

  // conv + SiLU -> u (bf16 only)
  conv_silu_kernel<<<(BL * DI / 4) / 256, 256, 0, stream>>>(xbuf, cw, cb, ub16);

  // GEMM2: x_dbl = u @ x_proj_w^T (M=4096, N=96, K=2048) + fused dt hi/lo split
  gemm_xproj<<<(256 * 6) / 4, 256, 0, stream>>>(ub16, wxp_b, xdbl, dt_hi, dt_lo);

  // GEMM3: delta = softplus(dt_lo @ dt_proj_w^T + b) via split-bf16 MFMA
  dt_gemm_mfma<<<(256 * 128) / 4, 256, 0, stream>>>(dt_hi, dt_lo, w_hi, w_lo, bdt, deltab);

  // chunked selective scan (thread-owns-channel layout)
  {
    dim3 gA(DI / 256, NC, Bsz);
    scan_chunk_ps<<<gA, 256, 0, stream>>>(deltab, ub16, xdbl, alog, Pbuf, Sbuf);
    scan_combine<<<(Bsz * DI * NS) / 256, 256, 0, stream>>>(Pbuf, Sbuf, Hin);
    scan_chunk_y<<<gA, 256, 0, stream>>>(deltab, ub16, xdbl, alog, dpar, zbuf, Hin, y_b);
  }

  // GEMM4: out = y @ out_proj_w^T  (M=4096, N=1024, K=2048) -> d_out f32
  {
    dim3 g(DM / 128, BL / 128);
    gemm128_bt<false><<<g, 256, 0, stream>>>(y_b, wout_b, out, out, DM, DM, DM, DI);
  }
}

// Round 7
// 291.791 us; speedup vs baseline: 7.7362x; 1.0079x over previous
//
#include <hip/hip_runtime.h>
#include <cstdint>
#include <cstddef>

// ---- problem constants ----
#define Bsz  2
#define Lseq 2048
#define DM   1024
#define DI   2048
#define NS   16
#define RR   64
#define BL   (Bsz * Lseq)   // 4096 rows
#define TC   64             // scan chunk length
#define NC   (Lseq / TC)    // 32 chunks

typedef unsigned short u16;
typedef __attribute__((ext_vector_type(4))) unsigned short u16x4;
typedef __attribute__((ext_vector_type(8))) short short8;   // 8 bf16 (4 VGPRs)
typedef __attribute__((ext_vector_type(4))) float f32x4;    // 4 f32 acc

__device__ __forceinline__ u16 f32_to_bf16(float f) {
  union { float f; unsigned int u; } v; v.f = f;
  unsigned int lsb = (v.u >> 16) & 1u;
  v.u += 0x7fffu + lsb;           // round-to-nearest-even
  return (u16)(v.u >> 16);
}
__device__ __forceinline__ float bf16_to_f32(u16 h) {
  union { unsigned int u; float f; } v; v.u = ((unsigned int)h) << 16;
  return v.f;
}

// ---------------- f32 -> bf16 conversion ----------------
__global__ void cvt_f32_bf16(const float* __restrict__ src, u16* __restrict__ dst, int n) {
  int i = (blockIdx.x * blockDim.x + threadIdx.x) * 4;
  if (i + 4 <= n) {
    float4 v = *(const float4*)(src + i);
    dst[i + 0] = f32_to_bf16(v.x);
    dst[i + 1] = f32_to_bf16(v.y);
    dst[i + 2] = f32_to_bf16(v.z);
    dst[i + 3] = f32_to_bf16(v.w);
  } else {
    for (; i < n; ++i) dst[i] = f32_to_bf16(src[i]);
  }
}

// ---------------- split f32 -> bf16 hi + bf16 lo (dtw weights) ----------------
__global__ void split_bf16_kernel(const float* __restrict__ src,
                                  u16* __restrict__ hi, u16* __restrict__ lo, int n) {
  int i = blockIdx.x * blockDim.x + threadIdx.x;
  if (i >= n) return;
  const float v = src[i];
  const u16 h = f32_to_bf16(v);
  hi[i] = h;
  lo[i] = f32_to_bf16(v - bf16_to_f32(h));
}

// ---------------- 128x128-tile bf16 MFMA GEMM (m97 structure) ----------------
// + bijective XCD swizzle (T1), block-uniform output select (occupancy fix),
// + optional split-K via blockIdx.z (kstride = full row stride, K = per-z length,
//   zstride = element offset per z in the f32 output).
__device__ __forceinline__ void gload_lds16(const u16* g, u16* l) {
  __builtin_amdgcn_global_load_lds(
      (const __attribute__((address_space(1))) unsigned int*)g,
      (__attribute__((address_space(3))) unsigned int*)l,
      16, 0, 0);
}

template<bool BF16OUT>
__global__ __launch_bounds__(256) void gemm128_bt(
    const u16* __restrict__ A, const u16* __restrict__ Bt,
    void* __restrict__ outA_, void* __restrict__ outB_,
    int split, int ldA, int ldB, int K, int kstride, size_t zstride)
{
  __shared__ __align__(16) u16 As[128 * 32];
  __shared__ __align__(16) u16 Bs[128 * 32];
  const int tid  = threadIdx.x;
  const int lane = tid & 63;
  const int wid  = tid >> 6;

  // bijective XCD swizzle (nwg % 8 == 0 for all call sites)
  const int nwg = gridDim.x * gridDim.y;
  int wg = blockIdx.y * gridDim.x + blockIdx.x;
  wg = (wg & 7) * (nwg >> 3) + (wg >> 3);
  const int m0 = (wg / gridDim.x) * 128;
  const int n0 = (wg % gridDim.x) * 128;
  const int kbase = blockIdx.z * K;

  const int wr = wid >> 1, wc = wid & 1;

  const f32x4 zero = {0.f, 0.f, 0.f, 0.f};
  f32x4 acc[4][4];
#pragma unroll
  for (int i = 0; i < 4; ++i)
#pragma unroll
    for (int j = 0; j < 4; ++j) acc[i][j] = zero;

  const int l16 = lane * 16;

  for (int k0 = 0; k0 < K; k0 += 32) {
    __syncthreads();
#pragma unroll
    for (int c = 0; c < 2; ++c) {
      const int base = c * 4096 + wid * 1024;
      const int ofs  = base + l16;
      const int row  = ofs >> 6;
      const int col  = (ofs >> 1) & 31;
      gload_lds16(A  + (size_t)(m0 + row) * kstride + kbase + k0 + col, (u16*)((char*)As + base));
      gload_lds16(Bt + (size_t)(n0 + row) * kstride + kbase + k0 + col, (u16*)((char*)Bs + base));
    }
    __syncthreads();

    const int kk = (lane >> 4) * 8;
    const int ra = wr * 64 + (lane & 15);
    const int rb = wc * 64 + (lane & 15);
    short8 af[4], bf[4];
#pragma unroll
    for (int i = 0; i < 4; ++i) af[i] = *(const short8*)&As[(ra + i * 16) * 32 + kk];
#pragma unroll
    for (int j = 0; j < 4; ++j) bf[j] = *(const short8*)&Bs[(rb + j * 16) * 32 + kk];
#pragma unroll
    for (int i = 0; i < 4; ++i)
#pragma unroll
      for (int j = 0; j < 4; ++j)
        acc[i][j] = __builtin_amdgcn_mfma_f32_16x16x32_bf16(af[i], bf[j], acc[i][j], 0, 0, 0);
  }

  // epilogue: block-uniform output select (SGPR), per-lane stores unconditional
  const bool isA = (n0 < split);
  const int  ld  = isA ? ldA : ldB;
  const int  nb  = isA ? n0 : n0 - split;
  const int cr = (lane >> 4) * 4;
  const int cc = lane & 15;
  if constexpr (BF16OUT) {
    u16* o = (u16*)(isA ? outA_ : outB_);
#pragma unroll
    for (int i = 0; i < 4; ++i)
#pragma unroll
      for (int j = 0; j < 4; ++j)
#pragma unroll
        for (int r = 0; r < 4; ++r) {
          const int m = m0 + wr * 64 + i * 16 + cr + r;
          const int n = nb + wc * 64 + j * 16 + cc;
          o[(size_t)m * ld + n] = f32_to_bf16(acc[i][j][r]);
        }
  } else {
    float* o = (float*)(isA ? outA_ : outB_) + (size_t)blockIdx.z * zstride;
#pragma unroll
    for (int i = 0; i < 4; ++i)
#pragma unroll
      for (int j = 0; j < 4; ++j)
#pragma unroll
        for (int r = 0; r < 4; ++r) {
          const int m = m0 + wr * 64 + i * 16 + cr + r;
          const int n = nb + wc * 64 + j * 16 + cc;
          o[(size_t)m * ld + n] = acc[i][j][r];
        }
  }
}

// ---------------- split-K partial sum: out = p0 + p1 (f32, vectorized) -------
__global__ void add2_kernel(const float* __restrict__ part, float* __restrict__ out) {
  const int i = (blockIdx.x * blockDim.x + threadIdx.x) * 4;
  const float4 a = *(const float4*)(part + i);
  const float4 b = *(const float4*)(part + (size_t)BL * DM + i);
  float4 s;
  s.x = a.x + b.x; s.y = a.y + b.y; s.z = a.z + b.z; s.w = a.w + b.w;
  *(float4*)(out + i) = s;
}

// ---------------- x_proj GEMM (N=96) + fused dt hi/lo split ----------------
__global__ __launch_bounds__(256) void gemm_xproj(
    const u16* __restrict__ A, const u16* __restrict__ Bt,
    float* __restrict__ xdbl, u16* __restrict__ dhi, u16* __restrict__ dlo)
{
  const int wg   = blockIdx.x * 4 + (threadIdx.x >> 6);   // over 256*6 tiles
  const int lane = threadIdx.x & 63;
  const int mt = wg / 6, nt = wg % 6;

  const u16* arow = A  + (size_t)(mt * 16 + (lane & 15)) * DI + ((lane >> 4) * 8);
  const u16* brow = Bt + (size_t)(nt * 16 + (lane & 15)) * DI + ((lane >> 4) * 8);
  f32x4 acc = {0.f, 0.f, 0.f, 0.f};
  for (int k0 = 0; k0 < DI; k0 += 32) {
    short8 a = *(const short8*)(arow + k0);
    short8 b = *(const short8*)(brow + k0);
    acc = __builtin_amdgcn_mfma_f32_16x16x32_bf16(a, b, acc, 0, 0, 0);
  }
  const int cr = (lane >> 4) * 4, cc = lane & 15;
  const int n  = nt * 16 + cc;
#pragma unroll
  for (int r = 0; r < 4; ++r) {
    const int m = mt * 16 + cr + r;
    const float v = acc[r];
    if (n < RR) {
      const u16 h = f32_to_bf16(v);
      dhi[(size_t)m * RR + n] = h;
      dlo[(size_t)m * RR + n] = f32_to_bf16(v - bf16_to_f32(h));
    } else {
      xdbl[(size_t)m * 96 + n] = v;
    }
  }
}

// ---------------- dt GEMM via split-bf16 MFMA + fused softplus ----------------
// s = a_hi*b_hi + a_hi*b_lo + a_lo*b_hi  (error ~1e-5, f32-equivalent here)
__global__ __launch_bounds__(256) void dt_gemm_mfma(
    const u16* __restrict__ ahi, const u16* __restrict__ alo,
    const u16* __restrict__ bhi, const u16* __restrict__ blo,
    const float* __restrict__ dtb, float* __restrict__ delta)
{
  const int wg   = blockIdx.x * 4 + (threadIdx.x >> 6);  // 256*128 tiles
  const int lane = threadIdx.x & 63;
  const int mt = wg >> 7, nt = wg & 127;

  const size_t aofs = (size_t)(mt * 16 + (lane & 15)) * 64 + ((lane >> 4) * 8);
  const size_t bofs = (size_t)(nt * 16 + (lane & 15)) * 64 + ((lane >> 4) * 8);

  f32x4 acc = {0.f, 0.f, 0.f, 0.f};
#pragma unroll
  for (int k0 = 0; k0 < 64; k0 += 32) {
    const short8 Ah = *(const short8*)(ahi + aofs + k0);
    const short8 Al = *(const short8*)(alo + aofs + k0);
    const short8 Bh = *(const short8*)(bhi + bofs + k0);
    const short8 Bl = *(const short8*)(blo + bofs + k0);
    acc = __builtin_amdgcn_mfma_f32_16x16x32_bf16(Ah, Bh, acc, 0, 0, 0);
    acc = __builtin_amdgcn_mfma_f32_16x16x32_bf16(Ah, Bl, acc, 0, 0, 0);
    acc = __builtin_amdgcn_mfma_f32_16x16x32_bf16(Al, Bh, acc, 0, 0, 0);
  }

  const int cr = (lane >> 4) * 4, cc = lane & 15;
  const int n  = nt * 16 + cc;
  const float b = dtb[n];
#pragma unroll
  for (int r = 0; r < 4; ++r) {
    const float s = acc[r] + b;
    // branch-free softplus: max(s,0) + log(1 + exp(-|s|)); abs err ~2^-24
    const float sp = fmaxf(s, 0.f) + __logf(1.f + __expf(-fabsf(s)));
    delta[(size_t)(mt * 16 + cr + r) * DI + n] = sp;
  }
}

// ---------------- causal depthwise conv (W=4) + bias + SiLU, bf16 in/out ----
__global__ void conv_silu_kernel(const u16* __restrict__ x,
                                 const float* __restrict__ cw, const float* __restrict__ cb,
                                 u16* __restrict__ ub)
{
  const int idx  = blockIdx.x * blockDim.x + threadIdx.x;   // over BL*DI/4
  const int base = idx * 4;
  const int d  = base & (DI - 1);
  const int bl = base >> 11;           // DI = 2048
  const int l  = bl & (Lseq - 1);      // Lseq = 2048
  const u16* xp = x + (size_t)bl * DI + d;
  const u16x4 zv = {0, 0, 0, 0};
  const u16x4 x3 = *(const u16x4*)xp;
  const u16x4 x2 = (l >= 1) ? *(const u16x4*)(xp - DI)     : zv;
  const u16x4 x1 = (l >= 2) ? *(const u16x4*)(xp - 2 * DI) : zv;
  const u16x4 x0 = (l >= 3) ? *(const u16x4*)(xp - 3 * DI) : zv;
  const float4 bias = *(const float4*)&cb[d];
  u16x4 out;
#pragma unroll
  for (int j = 0; j < 4; ++j) {
    const float4 w = *(const float4*)&cw[(d + j) * 4];
    float acc = ((const float*)&bias)[j];
    acc += bf16_to_f32(x0[j]) * w.x + bf16_to_f32(x1[j]) * w.y +
           bf16_to_f32(x2[j]) * w.z + bf16_to_f32(x3[j]) * w.w;
    const float s = acc / (1.f + __expf(-acc));   // SiLU
    out[j] = f32_to_bf16(s);
  }
  *(u16x4*)(ub + (size_t)bl * DI + d) = out;
}

// ================= chunked selective scan =================
// Thread-owns-channel layout; delta f32 (exp-sensitive), u/z bf16.

// ---- Kernel A: chunk-local products/partials ----
__global__ __launch_bounds__(256) void scan_chunk_ps(
    const float* __restrict__ delta, const u16* __restrict__ u,
    const float* __restrict__ xdbl, const float* __restrict__ alog,
    float* __restrict__ Pout, float* __restrict__ Sout)
{
  __shared__ float Bl[TC][NS];
  const int b   = blockIdx.z;
  const int c   = blockIdx.y;
  const int d   = blockIdx.x * 256 + threadIdx.x;
  const int tid = threadIdx.x;
  const size_t rowBase = (size_t)b * Lseq + (size_t)c * TC;

  {
    const int row = tid >> 2, c4 = (tid & 3) * 4;
    *(float4*)&Bl[row][c4] = *(const float4*)&xdbl[(rowBase + row) * 96 + RR + c4];
  }
  __syncthreads();

  float A[NS];
#pragma unroll
  for (int n4 = 0; n4 < 4; ++n4) {
    const float4 a4 = *(const float4*)&alog[(size_t)d * NS + n4 * 4];
    A[n4 * 4 + 0] = -__expf(a4.x);
    A[n4 * 4 + 1] = -__expf(a4.y);
    A[n4 * 4 + 2] = -__expf(a4.z);
    A[n4 * 4 + 3] = -__expf(a4.w);
  }

  float h[NS], P[NS];
#pragma unroll
  for (int n = 0; n < NS; ++n) { h[n] = 0.f; P[n] = 1.f; }

#pragma unroll 4
  for (int t = 0; t < TC; ++t) {
    const float dt  = delta[(rowBase + t) * DI + d];
    const float ut  = bf16_to_f32(u[(rowBase + t) * DI + d]);
    const float dtu = dt * ut;
#pragma unroll
    for (int n = 0; n < NS; ++n) {
      const float dA = __expf(dt * A[n]);
      P[n] *= dA;
      h[n] = dA * h[n] + dtu * Bl[t][n];
    }
  }

  const size_t base = (size_t)(b * NC + c) * NS * DI + d;
#pragma unroll
  for (int n = 0; n < NS; ++n) {
    Pout[base + (size_t)n * DI] = P[n];
    Sout[base + (size_t)n * DI] = h[n];
  }
}

// ---- Kernel B: inter-chunk combine (serial over NC only) ----
__global__ __launch_bounds__(256) void scan_combine(
    const float* __restrict__ P, const float* __restrict__ S,
    float* __restrict__ Hin)   // may alias P (per-thread read-before-write)
{
  const int gid = blockIdx.x * 256 + threadIdx.x;  // over Bsz*NS*DI = 65536
  const int b   = gid >> 15;                       // NS*DI = 32768
  const int nd  = gid & 32767;
  float h = 0.f;
  for (int c = 0; c < NC; ++c) {
    const size_t o = (size_t)(b * NC + c) * (NS * DI) + nd;
    const float Pc = P[o];
    const float Sc = S[o];
    Hin[o] = h;
    h = Pc * h + Sc;
  }
}

// ---- Kernel C: chunk-local y with seeded state, + skip + gate -> bf16 ----
// yb may alias u (per-thread read-ut-then-write-y at the same index).
__global__ __launch_bounds__(256) void scan_chunk_y(
    const float* __restrict__ delta, const u16* __restrict__ u,
    const float* __restrict__ xdbl, const float* __restrict__ alog,
    const float* __restrict__ dpar, const u16* __restrict__ z,
    const float* __restrict__ Hin, u16* __restrict__ yb)
{
  __shared__ float Bl[TC][NS];
  __shared__ float Cl[TC][NS];
  const int b   = blockIdx.z;
  const int c   = blockIdx.y;
  const int d   = blockIdx.x * 256 + threadIdx.x;
  const int tid = threadIdx.x;
  const size_t rowBase = (size_t)b * Lseq + (size_t)c * TC;

  {
    const int row = tid >> 2, c4 = (tid & 3) * 4;
    *(float4*)&Bl[row][c4] = *(const float4*)&xdbl[(rowBase + row) * 96 + RR + c4];
    *(float4*)&Cl[row][c4] = *(const float4*)&xdbl[(rowBase + row) * 96 + RR + NS + c4];
  }
  __syncthreads();

  float A[NS];
#pragma unroll
  for (int n4 = 0; n4 < 4; ++n4) {
    const float4 a4 = *(const float4*)&alog[(size_t)d * NS + n4 * 4];
    A[n4 * 4 + 0] = -__expf(a4.x);
    A[n4 * 4 + 1] = -__expf(a4.y);
    A[n4 * 4 + 2] = -__expf(a4.z);
    A[n4 * 4 + 3] = -__expf(a4.w);
  }
  const float Dv = dpar[d];

  float h[NS];
  const size_t sbase = (size_t)(b * NC + c) * NS * DI + d;
#pragma unroll
  for (int n = 0; n < NS; ++n) h[n] = Hin[sbase + (size_t)n * DI];

#pragma unroll 4
  for (int t = 0; t < TC; ++t) {
    const float dt  = delta[(rowBase + t) * DI + d];
    const float ut  = bf16_to_f32(u[(rowBase + t) * DI + d]);
    const float zv  = bf16_to_f32(z[(rowBase + t) * DI + d]);
    const float dtu = dt * ut;
    float y = 0.f;
#pragma unroll
    for (int n = 0; n < NS; ++n) {
      const float dA = __expf(dt * A[n]);
      h[n] = dA * h[n] + dtu * Bl[t][n];
      y += h[n] * Cl[t][n];
    }
    const float yv = y + ut * Dv;
    const float g  = zv / (1.f + __expf(-zv));   // z * sigmoid(z)
    yb[(rowBase + t) * DI + d] = f32_to_bf16(yv * g);
  }
}

// ---------------- host launcher ----------------
extern "C" void kernel_launch(void* const* d_in, const int* in_sizes, int n_in,
                              void* d_out, int out_size, void* d_ws, size_t ws_size,
                              hipStream_t stream)
{
  const float* hs   = (const float*)d_in[0];  // (B,L,DM)
  const float* win  = (const float*)d_in[1];  // (2*DI, DM)
  const float* cw   = (const float*)d_in[2];  // (DI, 4)
  const float* cb   = (const float*)d_in[3];  // (DI,)
  const float* wxp  = (const float*)d_in[4];  // (96, DI)
  const float* wdt  = (const float*)d_in[5];  // (DI, 64)
  const float* bdt  = (const float*)d_in[6];  // (DI,)
  const float* alog = (const float*)d_in[7];  // (DI, NS)
  const float* dpar = (const float*)d_in[8];  // (DI,)
  const float* wout = (const float*)d_in[9];  // (DM, DI)
  float* out = (float*)d_out;                 // (B,L,DM) f32

  char* ws = (char*)d_ws;
  size_t off = 0;
  auto alloc = [&](size_t bytes) -> void* {
    void* p = ws + off;
    off += (bytes + 255) & ~(size_t)255;
    return p;
  };
  u16*   hs_b   = (u16*)  alloc((size_t)BL * DM * 2);        // 8 MB
  u16*   win_b  = (u16*)  alloc((size_t)2 * DI * DM * 2);    // 8 MB
  u16*   wxp_b  = (u16*)  alloc((size_t)96 * DI * 2);        // 0.4 MB
  u16*   wout_b = (u16*)  alloc((size_t)DM * DI * 2);        // 4 MB
  u16*   xbuf   = (u16*)  alloc((size_t)BL * DI * 2);        // 16 MB (bf16 x)
  u16*   zbuf   = (u16*)  alloc((size_t)BL * DI * 2);        // 16 MB (bf16 z)
  u16*   ub16   = (u16*)  alloc((size_t)BL * DI * 2);        // 16 MB (bf16 u)
  float* deltab = (float*)alloc((size_t)BL * DI * 4);        // 32 MB (f32 delta)
  float* xdbl   = (float*)alloc((size_t)BL * 96 * 4);        // 1.5 MB
  float* Pbuf   = (float*)alloc((size_t)Bsz * NC * DI * NS * 4);  // 8.4 MB
  float* Sbuf   = (float*)alloc((size_t)Bsz * NC * DI * NS * 4);  // 8.4 MB
  u16*   dt_hi  = (u16*)  alloc((size_t)BL * 64 * 2);        // 0.5 MB
  u16*   dt_lo  = (u16*)  alloc((size_t)BL * 64 * 2);        // 0.5 MB
  u16*   w_hi   = (u16*)  alloc((size_t)DI * 64 * 2);        // 0.25 MB
  u16*   w_lo   = (u16*)  alloc((size_t)DI * 64 * 2);        // 0.25 MB
  u16*   y_b    = ub16;   // alias: scan_y reads u[t] then writes y[t], same thread/index
  float* Hin    = Pbuf;   // alias: scan_combine does per-thread read-P-then-write-Hin
  // GEMM4 split-K partials (2 x BL x DM f32 = 33.55 MB) alias deltab
  // (BL x DI f32 = 33.55 MB exactly); delta is dead after scan_chunk_y.
  float* part   = deltab;

  const int thr = 256;
  cvt_f32_bf16<<<(BL * DM / 4 + thr - 1) / thr, thr, 0, stream>>>(hs, hs_b, BL * DM);
  cvt_f32_bf16<<<(2 * DI * DM / 4 + thr - 1) / thr, thr, 0, stream>>>(win, win_b, 2 * DI * DM);
  cvt_f32_bf16<<<(96 * DI / 4 + thr - 1) / thr, thr, 0, stream>>>(wxp, wxp_b, 96 * DI);
  cvt_f32_bf16<<<(DM * DI / 4 + thr - 1) / thr, thr, 0, stream>>>(wout, wout_b, DM * DI);
  split_bf16_kernel<<<(DI * 64) / thr, thr, 0, stream>>>(wdt, w_hi, w_lo, DI * 64);

  // GEMM1: xz = hs @ in_proj_w^T  (M=4096, N=4096, K=1024) -> bf16 x | bf16 z
  {
    dim3 g(4096 / 128, BL / 128);   // nwg = 1024, %8 == 0
    gemm128_bt<true><<<g, 256, 0, stream>>>(hs_b, win_b, xbuf, zbuf,
                                            DI, DI, DI, DM, DM, 0);
  }

  // conv + SiLU -> u (bf16 only)
  conv_silu_kernel<<<(BL * DI / 4) / 256, 256, 0, stream>>>(xbuf, cw, cb, ub16);

  // GEMM2: x_dbl = u @ x_proj_w^T (M=4096, N=96, K=2048) + fused dt hi/lo split
  gemm_xproj<<<(256 * 6) / 4, 256, 0, stream>>>(ub16, wxp_b, xdbl, dt_hi, dt_lo);

  // GEMM3: delta = softplus(dt_lo @ dt_proj_w^T + b) via split-bf16 MFMA
  dt_gemm_mfma<<<(256 * 128) / 4, 256, 0, stream>>>(dt_hi, dt_lo, w_hi, w_lo, bdt, deltab);

  // chunked selective scan (thread-owns-channel layout)
  {
    dim3 gA(DI / 256, NC, Bsz);
    scan_chunk_ps<<<gA, 256, 0, stream>>>(deltab, ub16, xdbl, alog, Pbuf, Sbuf);
    scan_combine<<<(Bsz * DI * NS) / 256, 256, 0, stream>>>(Pbuf, Sbuf, Hin);
    scan_chunk_y<<<gA, 256, 0, stream>>>(deltab, ub16, xdbl, alog, dpar, zbuf, Hin, y_b);
  }

  // GEMM4: out = y @ out_proj_w^T (M=4096, N=1024, K=2048), split-K=2 -> f32 partials
  {
    dim3 g(DM / 128, BL / 128, 2);  // nwg_xy = 256, %8 == 0; z = K-split
    gemm128_bt<false><<<g, 256, 0, stream>>>(y_b, wout_b, part, part,
                                             1 << 30, DM, DM, DI / 2, DI,
                                             (size_t)BL * DM);
    add2_kernel<<<(BL * DM / 4) / 256, 256, 0, stream>>>(part, out);
  }
}